// Round 1
// baseline (1388.221 us; speedup 1.0000x reference)
//
#include <hip/hip_runtime.h>
#include <hip/hip_bf16.h>

typedef __attribute__((ext_vector_type(8))) short bf16x8;
typedef __attribute__((ext_vector_type(4))) float f32x4;

#define MFMA16(a, b, c) __builtin_amdgcn_mfma_f32_16x16x32_bf16((a), (b), (c), 0, 0, 0)

static __device__ __forceinline__ unsigned short f2b(float f) {
  union { __hip_bfloat16 h; unsigned short u; } cv;
  cv.h = __float2bfloat16(f);
  return cv.u;
}

// Convert Wq,Wk,Wv ([8][64][512] each) and Wo ([512][512]) fp32 -> bf16 into ws.
// ws layout: [3][8][64][512] bf16 (QKV), then [512][512] bf16 (Wo) at +786432.
__global__ __launch_bounds__(256) void prep_weights(
    const float* __restrict__ Wq, const float* __restrict__ Wk,
    const float* __restrict__ Wv, const float* __restrict__ Wo,
    unsigned short* __restrict__ dst) {
  int i = blockIdx.x * 256 + threadIdx.x;   // 262144 threads, 4 elems each
  int seg = i >> 16;                        // 0..3
  int off = (i & 65535) << 2;
  const float* src = (seg == 0) ? Wq : (seg == 1) ? Wk : (seg == 2) ? Wv : Wo;
  float4 v = *reinterpret_cast<const float4*>(src + off);
  ushort4 o = make_ushort4(f2b(v.x), f2b(v.y), f2b(v.z), f2b(v.w));
  *reinterpret_cast<ushort4*>(dst + (seg << 18) + off) = o;
}

// One block per window (2048 blocks), 512 threads = 8 waves.
__global__ __launch_bounds__(512) void swin_fused(
    const float* __restrict__ patches,
    const float* __restrict__ bq, const float* __restrict__ bk,
    const float* __restrict__ bv, const float* __restrict__ bo,
    const float* __restrict__ posb,
    const unsigned short* __restrict__ Wbf,
    float* __restrict__ out) {
  // LDS. Row strides: Xs 520 bf16 = 1040 B (16B-aligned, 2-way bank alias = free),
  // 64x72 tiles = 144 B rows (16B-aligned, 2-way alias).
  __shared__ unsigned short Xs[64][520];
  __shared__ unsigned short Qs[64][72];
  __shared__ unsigned short Ks[64][72];
  __shared__ unsigned short Vt[64][72];   // V transposed: Vt[d][q]
  __shared__ unsigned short Ps[64][72];
  __shared__ unsigned short Rs[64][72];
  __shared__ float2 pex[2][64];           // (local max, local sumexp) per col-half per row
  __shared__ float pb[232];               // pos_bias 15x15

  const int tid = threadIdx.x;
  const int bid = blockIdx.x;             // ((b*16+y)*16+x)
  const int wx = bid & 15;
  const int wy = (bid >> 4) & 15;
  const int w = tid >> 6;                 // wave 0..7
  const int lane = tid & 63;
  const int lr = lane & 15;
  const int kq = lane >> 4;

  const f32x4 zero4 = {0.f, 0.f, 0.f, 0.f};

  // ---- stage X: [64][512] fp32 -> bf16 LDS ----
  const float* Xg = patches + (size_t)bid * (64 * 512);
#pragma unroll
  for (int it = 0; it < 8; ++it) {
    int c = tid + it * 512;
    int p = c >> 6;
    int e0 = (c & 63) << 3;
    const float4* gp = reinterpret_cast<const float4*>(Xg + p * 512 + e0);
    float4 v0 = gp[0];
    float4 v1 = gp[1];
    bf16x8 xv;
    xv[0] = (short)f2b(v0.x); xv[1] = (short)f2b(v0.y);
    xv[2] = (short)f2b(v0.z); xv[3] = (short)f2b(v0.w);
    xv[4] = (short)f2b(v1.x); xv[5] = (short)f2b(v1.y);
    xv[6] = (short)f2b(v1.z); xv[7] = (short)f2b(v1.w);
    *reinterpret_cast<bf16x8*>(&Xs[p][e0]) = xv;
  }
  if (tid < 225) pb[tid] = posb[tid];
  __syncthreads();

  const int m = w & 3;      // attn row-strip (16 rows)
  const int half = w >> 2;  // attn col-half (32 cols)

  f32x4 acc_out[4][4];      // out[16*m2 + 4*kq + r][64*w + 16*n2 + lr]
#pragma unroll
  for (int i = 0; i < 4; ++i)
#pragma unroll
    for (int j = 0; j < 4; ++j)
      acc_out[i][j] = zero4;

  for (int h = 0; h < 8; ++h) {
    // ================= QKV projections =================
    // Waves 0,1: Q (row-halves 0,1); waves 2,3: K; waves 4..7: V (row-quarters).
    if (w < 4) {
      const int g = w >> 1;   // 0=Q, 1=K
      const int mh = w & 1;
      const unsigned short* Wg = Wbf + (size_t)((g * 8 + h) * 64) * 512;
      f32x4 acc[2][4];
#pragma unroll
      for (int mm = 0; mm < 2; ++mm)
#pragma unroll
        for (int nq = 0; nq < 4; ++nq)
          acc[mm][nq] = zero4;
#pragma unroll
      for (int kk = 0; kk < 16; ++kk) {
        int ko = kk * 32 + kq * 8;
        bf16x8 a0 = *reinterpret_cast<const bf16x8*>(&Xs[32 * mh + lr][ko]);
        bf16x8 a1 = *reinterpret_cast<const bf16x8*>(&Xs[32 * mh + 16 + lr][ko]);
#pragma unroll
        for (int nq = 0; nq < 4; ++nq) {
          bf16x8 wb = *reinterpret_cast<const bf16x8*>(Wg + (size_t)(16 * nq + lr) * 512 + ko);
          acc[0][nq] = MFMA16(a0, wb, acc[0][nq]);
          acc[1][nq] = MFMA16(a1, wb, acc[1][nq]);
        }
      }
      const float* bgp = (g == 0) ? bq : bk;
#pragma unroll
      for (int nq = 0; nq < 4; ++nq) {
        float bb = bgp[h * 64 + 16 * nq + lr];
        if (g == 0) {
#pragma unroll
          for (int mm = 0; mm < 2; ++mm)
#pragma unroll
            for (int r = 0; r < 4; ++r)
              Qs[32 * mh + 16 * mm + 4 * kq + r][16 * nq + lr] = f2b(acc[mm][nq][r] + bb);
        } else {
#pragma unroll
          for (int mm = 0; mm < 2; ++mm)
#pragma unroll
            for (int r = 0; r < 4; ++r)
              Ks[32 * mh + 16 * mm + 4 * kq + r][16 * nq + lr] = f2b(acc[mm][nq][r] + bb);
        }
      }
    } else {
      const int mq = w - 4;   // V row-quarter
      const unsigned short* Wg = Wbf + (size_t)((16 + h) * 64) * 512;
      f32x4 acc[4];
#pragma unroll
      for (int nq = 0; nq < 4; ++nq) acc[nq] = zero4;
#pragma unroll
      for (int kk = 0; kk < 16; ++kk) {
        int ko = kk * 32 + kq * 8;
        bf16x8 a0 = *reinterpret_cast<const bf16x8*>(&Xs[16 * mq + lr][ko]);
#pragma unroll
        for (int nq = 0; nq < 4; ++nq) {
          bf16x8 wb = *reinterpret_cast<const bf16x8*>(Wg + (size_t)(16 * nq + lr) * 512 + ko);
          acc[nq] = MFMA16(a0, wb, acc[nq]);
        }
      }
#pragma unroll
      for (int nq = 0; nq < 4; ++nq) {
        float bb = bv[h * 64 + 16 * nq + lr];
#pragma unroll
        for (int r = 0; r < 4; ++r)
          Vt[16 * nq + lr][16 * mq + 4 * kq + r] = f2b(acc[nq][r] + bb);  // transposed
      }
    }
    __syncthreads();

    // ================= S = Q K^T / 8 + bias, mask =================
    // wave (m, half): rows 16m..16m+16, cols 32*half..+32 (2 col-tiles)
    f32x4 sA[2];
    sA[0] = zero4; sA[1] = zero4;
#pragma unroll
    for (int ks = 0; ks < 2; ++ks) {
      int ko = ks * 32 + kq * 8;
      bf16x8 qa = *reinterpret_cast<const bf16x8*>(&Qs[16 * m + lr][ko]);
#pragma unroll
      for (int nn = 0; nn < 2; ++nn) {
        bf16x8 kf = *reinterpret_cast<const bf16x8*>(&Ks[32 * half + 16 * nn + lr][ko]);
        sA[nn] = MFMA16(qa, kf, sA[nn]);
      }
    }
    float vals[2][4];
#pragma unroll
    for (int nn = 0; nn < 2; ++nn)
#pragma unroll
      for (int r = 0; r < 4; ++r) {
        int p = 16 * m + 4 * kq + r;
        int q = 32 * half + 16 * nn + lr;
        int pr = p >> 3, pc = p & 7, qr = q >> 3, qc = q & 7;
        float val = sA[nn][r] * 0.125f + pb[(pr - qr + 7) * 15 + (pc - qc + 7)];
        bool mk = ((wy == 15) && ((pr < 4) != (qr < 4))) ||
                  ((wx == 15) && ((pc < 4) != (qc < 4)));
        vals[nn][r] = mk ? -1e30f : val;
      }
    // ---- two-half online softmax ----
    float lm[4], pe0[4], pe1[4];
#pragma unroll
    for (int r = 0; r < 4; ++r) {
      float t = fmaxf(vals[0][r], vals[1][r]);
      t = fmaxf(t, __shfl_xor(t, 1));
      t = fmaxf(t, __shfl_xor(t, 2));
      t = fmaxf(t, __shfl_xor(t, 4));
      t = fmaxf(t, __shfl_xor(t, 8));
      lm[r] = t;
      pe0[r] = __expf(vals[0][r] - t);
      pe1[r] = __expf(vals[1][r] - t);
      float s = pe0[r] + pe1[r];
      s += __shfl_xor(s, 1);
      s += __shfl_xor(s, 2);
      s += __shfl_xor(s, 4);
      s += __shfl_xor(s, 8);
      if (lr == 0) pex[half][16 * m + 4 * kq + r] = make_float2(t, s);
    }
    __syncthreads();
    float sinv[4];
#pragma unroll
    for (int r = 0; r < 4; ++r) {
      int row = 16 * m + 4 * kq + r;
      float2 ea = pex[0][row];
      float2 eb = pex[1][row];
      float M = fmaxf(ea.x, eb.x);
      float Sd = ea.y * __expf(ea.x - M) + eb.y * __expf(eb.x - M);
      float f = __expf(lm[r] - M);
      sinv[r] = 1.0f / Sd;
      Ps[row][32 * half + lr] = f2b(pe0[r] * f);
      Ps[row][32 * half + 16 + lr] = f2b(pe1[r] * f);
    }
    __syncthreads();

    // ================= R = softmax(S) V =================
    f32x4 rv[2];
    rv[0] = zero4; rv[1] = zero4;
#pragma unroll
    for (int ks = 0; ks < 2; ++ks) {
      int ko = ks * 32 + kq * 8;
      bf16x8 pa = *reinterpret_cast<const bf16x8*>(&Ps[16 * m + lr][ko]);
#pragma unroll
      for (int nn = 0; nn < 2; ++nn) {
        bf16x8 vb = *reinterpret_cast<const bf16x8*>(&Vt[32 * half + 16 * nn + lr][ko]);
        rv[nn] = MFMA16(pa, vb, rv[nn]);
      }
    }
#pragma unroll
    for (int nn = 0; nn < 2; ++nn)
#pragma unroll
      for (int r = 0; r < 4; ++r)
        Rs[16 * m + 4 * kq + r][32 * half + 16 * nn + lr] = f2b(rv[nn][r] * sinv[r]);
    __syncthreads();

    // ================= out += R_h @ Wo[:, h*64:h*64+64]^T =================
    // wave w owns out cols 64w..64w+64
    const unsigned short* WoB = Wbf + 786432;
#pragma unroll
    for (int ks = 0; ks < 2; ++ks) {
      int ko = ks * 32 + kq * 8;
      bf16x8 ra[4];
#pragma unroll
      for (int m2 = 0; m2 < 4; ++m2)
        ra[m2] = *reinterpret_cast<const bf16x8*>(&Rs[16 * m2 + lr][ko]);
#pragma unroll
      for (int n2 = 0; n2 < 4; ++n2) {
        bf16x8 wob = *reinterpret_cast<const bf16x8*>(
            WoB + (size_t)(64 * w + 16 * n2 + lr) * 512 + h * 64 + ko);
#pragma unroll
        for (int m2 = 0; m2 < 4; ++m2)
          acc_out[m2][n2] = MFMA16(ra[m2], wob, acc_out[m2][n2]);
      }
    }
    __syncthreads();
  }

  // ---- epilogue: + bo, store fp32 ----
  float* outg = out + (size_t)bid * (64 * 512);
#pragma unroll
  for (int n2 = 0; n2 < 4; ++n2) {
    float bov = bo[64 * w + 16 * n2 + lr];
#pragma unroll
    for (int m2 = 0; m2 < 4; ++m2)
#pragma unroll
      for (int r = 0; r < 4; ++r)
        outg[(size_t)(16 * m2 + 4 * kq + r) * 512 + 64 * w + 16 * n2 + lr] =
            acc_out[m2][n2][r] + bov;
  }
}

extern "C" void kernel_launch(void* const* d_in, const int* in_sizes, int n_in,
                              void* d_out, int out_size, void* d_ws, size_t ws_size,
                              hipStream_t stream) {
  const float* patches = (const float*)d_in[0];
  const float* Wq = (const float*)d_in[1];
  const float* bq = (const float*)d_in[2];
  const float* Wk = (const float*)d_in[3];
  const float* bk = (const float*)d_in[4];
  const float* Wv = (const float*)d_in[5];
  const float* bv = (const float*)d_in[6];
  const float* Wo = (const float*)d_in[7];
  const float* bo = (const float*)d_in[8];
  const float* posb = (const float*)d_in[9];
  // mask (d_in[10]) and bias_idx (d_in[11],[12]) are deterministic; recomputed on device.
  unsigned short* wbf = (unsigned short*)d_ws;   // needs 2 MiB
  hipLaunchKernelGGL(prep_weights, dim3(1024), dim3(256), 0, stream, Wq, Wk, Wv, Wo, wbf);
  hipLaunchKernelGGL(swin_fused, dim3(2048), dim3(512), 0, stream,
                     patches, bq, bk, bv, bo, posb, wbf, (float*)d_out);
}

// Round 3
// 600.906 us; speedup vs baseline: 2.3102x; 2.3102x over previous
//
#include <hip/hip_runtime.h>
#include <hip/hip_bf16.h>

typedef __attribute__((ext_vector_type(8))) short bf16x8;
typedef __attribute__((ext_vector_type(16))) float f32x16;
typedef __attribute__((ext_vector_type(4))) unsigned int u32x4;

#define MFMA32(a, b, c) __builtin_amdgcn_mfma_f32_32x32x16_bf16((a), (b), (c), 0, 0, 0)

static __device__ __forceinline__ unsigned short f2b(float f) {
  union { __hip_bfloat16 h; unsigned short u; } cv;
  cv.h = __float2bfloat16(f);
  return cv.u;
}

static __device__ __forceinline__ unsigned int pkbf(float lo, float hi) {
  unsigned int r;
  asm("v_cvt_pk_bf16_f32 %0, %1, %2" : "=v"(r) : "v"(lo), "v"(hi));
  return r;
}

static __device__ __forceinline__ bf16x8 u4_to_bf8(u32x4 u) {
  union { u32x4 u; bf16x8 b; } cv;
  cv.u = u;
  return cv.b;
}

static __device__ __forceinline__ f32x16 z16() {
  f32x16 z;
#pragma unroll
  for (int i = 0; i < 16; ++i) z[i] = 0.0f;
  return z;
}

// Convert one 32x32 MFMA C-tile (value at [row=(r&3)+8*(r>>2)+4*hi][col=lane&31])
// into two bf16 frags with k-runs taken from the ROW dim:
// f0 covers local-k = 8*hi + {0..7}, f1 covers 16 + 8*hi + {0..7}. Column (lane&31)
// association is preserved. Uses cvt_pk + shfl_xor(32) (lanes l and l^32 hold the
// same column, offset by 4 in row).
static __device__ __forceinline__ void tile2frag(const f32x16 t, int hi,
                                                 bf16x8* f0, bf16x8* f1) {
  unsigned int a0 = pkbf(t[0], t[1]), a1 = pkbf(t[2], t[3]);
  unsigned int b0 = pkbf(t[4], t[5]), b1 = pkbf(t[6], t[7]);
  unsigned int c0 = pkbf(t[8], t[9]), c1 = pkbf(t[10], t[11]);
  unsigned int d0 = pkbf(t[12], t[13]), d1 = pkbf(t[14], t[15]);
  unsigned int sa0 = __shfl_xor((int)a0, 32), sa1 = __shfl_xor((int)a1, 32);
  unsigned int sb0 = __shfl_xor((int)b0, 32), sb1 = __shfl_xor((int)b1, 32);
  unsigned int sc0 = __shfl_xor((int)c0, 32), sc1 = __shfl_xor((int)c1, 32);
  unsigned int sd0 = __shfl_xor((int)d0, 32), sd1 = __shfl_xor((int)d1, 32);
  u32x4 fa, fb;
  fa[0] = hi ? sb0 : a0; fa[1] = hi ? sb1 : a1;
  fa[2] = hi ? b0 : sa0; fa[3] = hi ? b1 : sa1;
  fb[0] = hi ? sd0 : c0; fb[1] = hi ? sd1 : c1;
  fb[2] = hi ? d0 : sc0; fb[3] = hi ? d1 : sc1;
  *f0 = u4_to_bf8(fa);
  *f1 = u4_to_bf8(fb);
}

// T = (X @ Wg^T + bg)^T computed as mfma(A=Wg rows, B=X rows): C rows = d, cols = token.
// Emits frags: frag[tcol][kd] = rows token (lane&31)+32*tcol over d-run 16*kd+8*hi+{0..7}.
static __device__ __forceinline__ void projT(
    const unsigned short* __restrict__ Wg, const float* __restrict__ bg,
    const unsigned short* Xs, int l31, int hi, bf16x8 frag[2][4]) {
  f32x16 c00 = z16(), c01 = z16(), c10 = z16(), c11 = z16();  // c[td][tq]
  const int sw = (l31 & 7) << 3;
  const unsigned short* xr0 = Xs + l31 * 512;
  const unsigned short* xr1 = Xs + (l31 + 32) * 512;
  const unsigned short* wr0 = Wg + (size_t)l31 * 512;
  const unsigned short* wr1 = Wg + (size_t)(l31 + 32) * 512;
#pragma unroll 2
  for (int ke = 0; ke < 32; ++ke) {
    const int eo = 8 * hi + 16 * ke;
    bf16x8 x0 = *reinterpret_cast<const bf16x8*>(xr0 + (eo ^ sw));
    bf16x8 x1 = *reinterpret_cast<const bf16x8*>(xr1 + (eo ^ sw));
    bf16x8 w0 = *reinterpret_cast<const bf16x8*>(wr0 + eo);
    bf16x8 w1 = *reinterpret_cast<const bf16x8*>(wr1 + eo);
    c00 = MFMA32(w0, x0, c00); c01 = MFMA32(w0, x1, c01);
    c10 = MFMA32(w1, x0, c10); c11 = MFMA32(w1, x1, c11);
  }
#pragma unroll
  for (int q2 = 0; q2 < 4; ++q2) {
    float4 b0 = *reinterpret_cast<const float4*>(bg + 8 * q2 + 4 * hi);
    float4 b1 = *reinterpret_cast<const float4*>(bg + 32 + 8 * q2 + 4 * hi);
    c00[4 * q2 + 0] += b0.x; c00[4 * q2 + 1] += b0.y;
    c00[4 * q2 + 2] += b0.z; c00[4 * q2 + 3] += b0.w;
    c01[4 * q2 + 0] += b0.x; c01[4 * q2 + 1] += b0.y;
    c01[4 * q2 + 2] += b0.z; c01[4 * q2 + 3] += b0.w;
    c10[4 * q2 + 0] += b1.x; c10[4 * q2 + 1] += b1.y;
    c10[4 * q2 + 2] += b1.z; c10[4 * q2 + 3] += b1.w;
    c11[4 * q2 + 0] += b1.x; c11[4 * q2 + 1] += b1.y;
    c11[4 * q2 + 2] += b1.z; c11[4 * q2 + 3] += b1.w;
  }
  tile2frag(c00, hi, &frag[0][0], &frag[0][1]);
  tile2frag(c10, hi, &frag[0][2], &frag[0][3]);
  tile2frag(c01, hi, &frag[1][0], &frag[1][1]);
  tile2frag(c11, hi, &frag[1][2], &frag[1][3]);
}

// Score scale + bias/mask + softmax for one query-column-tile (tp).
// A lane holds only HALF the keys (hi-interleaved rows); lane l^32 holds the
// complement for the SAME query -> must combine max/sum across the pair.
static __device__ __forceinline__ float sm_tp(f32x16& t0, f32x16& t1,
                                              const float* BmRow, int hi) {
#pragma unroll
  for (int q2 = 0; q2 < 4; ++q2) {
    float4 b0 = *reinterpret_cast<const float4*>(BmRow + 8 * q2 + 4 * hi);
    float4 b1 = *reinterpret_cast<const float4*>(BmRow + 32 + 8 * q2 + 4 * hi);
    t0[4 * q2 + 0] = fmaf(t0[4 * q2 + 0], 0.125f, b0.x);
    t0[4 * q2 + 1] = fmaf(t0[4 * q2 + 1], 0.125f, b0.y);
    t0[4 * q2 + 2] = fmaf(t0[4 * q2 + 2], 0.125f, b0.z);
    t0[4 * q2 + 3] = fmaf(t0[4 * q2 + 3], 0.125f, b0.w);
    t1[4 * q2 + 0] = fmaf(t1[4 * q2 + 0], 0.125f, b1.x);
    t1[4 * q2 + 1] = fmaf(t1[4 * q2 + 1], 0.125f, b1.y);
    t1[4 * q2 + 2] = fmaf(t1[4 * q2 + 2], 0.125f, b1.z);
    t1[4 * q2 + 3] = fmaf(t1[4 * q2 + 3], 0.125f, b1.w);
  }
  float mx = t0[0];
#pragma unroll
  for (int r = 1; r < 16; ++r) mx = fmaxf(mx, t0[r]);
#pragma unroll
  for (int r = 0; r < 16; ++r) mx = fmaxf(mx, t1[r]);
  mx = fmaxf(mx, __shfl_xor(mx, 32));   // combine the two key-halves (FIX)
  float sum = 0.f;
#pragma unroll
  for (int r = 0; r < 16; ++r) { t0[r] = __expf(t0[r] - mx); sum += t0[r]; }
#pragma unroll
  for (int r = 0; r < 16; ++r) { t1[r] = __expf(t1[r] - mx); sum += t1[r]; }
  sum += __shfl_xor(sum, 32);           // combine the two key-halves (FIX)
  return 1.0f / sum;
}

// Weights fp32 -> bf16: [3][8][64][512] (QKV) then Wo [512][512] at +786432.
__global__ __launch_bounds__(256) void prep_weights(
    const float* __restrict__ Wq, const float* __restrict__ Wk,
    const float* __restrict__ Wv, const float* __restrict__ Wo,
    unsigned short* __restrict__ dst) {
  int i = blockIdx.x * 256 + threadIdx.x;
  int seg = i >> 16;
  int off = (i & 65535) << 2;
  const float* src = (seg == 0) ? Wq : (seg == 1) ? Wk : (seg == 2) ? Wv : Wo;
  float4 v = *reinterpret_cast<const float4*>(src + off);
  ushort4 o = make_ushort4(f2b(v.x), f2b(v.y), f2b(v.z), f2b(v.w));
  *reinterpret_cast<ushort4*>(dst + (seg << 18) + off) = o;
}

// One block per window (2048 blocks), 512 threads = 8 waves, wave w = head w.
__global__ __launch_bounds__(512, 2) void swin_fused(
    const float* __restrict__ patches,
    const float* __restrict__ bq, const float* __restrict__ bk,
    const float* __restrict__ bv, const float* __restrict__ bo,
    const float* __restrict__ posb,
    const unsigned short* __restrict__ Wbf,
    float* __restrict__ out) {
  // XsRs: X bf16 [64][512] (swizzled), later aliased by Rs [64][512] (same swizzle).
  __shared__ unsigned short XsRs[64 * 512];   // 64 KiB
  __shared__ unsigned short VtAll[8 * 64 * 64]; // per-wave V^T [d][q], 64 KiB
  __shared__ float Bm[64][68];                 // bias+mask [query][key], 17 KiB

  const int tid = threadIdx.x;
  const int bid = blockIdx.x;                  // ((b*16+y)*16+x)
  const int wxi = bid & 15;
  const int wyi = (bid >> 4) & 15;
  const int w = tid >> 6;
  const int lane = tid & 63;
  const int l31 = lane & 31;
  const int hi = lane >> 5;
  const int h = w;

  // ---- Phase A: stage X (fp32->bf16, XOR-swizzled) + build Bm ----
  const float* Xg = patches + (size_t)bid * 32768;
#pragma unroll
  for (int it = 0; it < 8; ++it) {
    int p = it * 8 + (tid >> 6);
    int e0 = (tid & 63) << 3;
    const float4* gp = reinterpret_cast<const float4*>(Xg + p * 512 + e0);
    float4 v0 = gp[0], v1 = gp[1];
    u32x4 xv;
    xv[0] = pkbf(v0.x, v0.y); xv[1] = pkbf(v0.z, v0.w);
    xv[2] = pkbf(v1.x, v1.y); xv[3] = pkbf(v1.z, v1.w);
    *reinterpret_cast<u32x4*>(XsRs + p * 512 + (e0 ^ ((p & 7) << 3))) = xv;
  }
#pragma unroll
  for (int ii = 0; ii < 8; ++ii) {
    int i = ii * 512 + tid;
    int p = i >> 6, k = i & 63;
    int pr = p >> 3, pc = p & 7, kr = k >> 3, kc = k & 7;
    float b = posb[(pr - kr + 7) * 15 + (pc - kc + 7)];
    bool mk = ((wyi == 15) && ((pr < 4) != (kr < 4))) ||
              ((wxi == 15) && ((pc < 4) != (kc < 4)));
    Bm[p][k] = mk ? -1e30f : b;
  }
  __syncthreads();

  // ---- Phase B (per wave, head h): projections ----
  bf16x8 kf[2][4], qf[2][4];
  projT(Wbf + (size_t)(8 + h) * 32768, bk + h * 64, XsRs, l31, hi, kf);
  projT(Wbf + (size_t)(0 + h) * 32768, bq + h * 64, XsRs, l31, hi, qf);

  // V = mfma(A=X rows, B=Wv rows): C rows = token q, cols = d. Write V^T to LDS.
  {
    f32x16 v00 = z16(), v01 = z16(), v10 = z16(), v11 = z16();  // v[tq][td]
    const int sw = (l31 & 7) << 3;
    const unsigned short* xr0 = XsRs + l31 * 512;
    const unsigned short* xr1 = XsRs + (l31 + 32) * 512;
    const unsigned short* wr0 = Wbf + (size_t)(16 + h) * 32768 + (size_t)l31 * 512;
    const unsigned short* wr1 = wr0 + (size_t)32 * 512;
#pragma unroll 2
    for (int ke = 0; ke < 32; ++ke) {
      const int eo = 8 * hi + 16 * ke;
      bf16x8 x0 = *reinterpret_cast<const bf16x8*>(xr0 + (eo ^ sw));
      bf16x8 x1 = *reinterpret_cast<const bf16x8*>(xr1 + (eo ^ sw));
      bf16x8 w0 = *reinterpret_cast<const bf16x8*>(wr0 + eo);
      bf16x8 w1 = *reinterpret_cast<const bf16x8*>(wr1 + eo);
      v00 = MFMA32(x0, w0, v00); v01 = MFMA32(x0, w1, v01);
      v10 = MFMA32(x1, w0, v10); v11 = MFMA32(x1, w1, v11);
    }
    float bv0 = bv[h * 64 + l31];
    float bv1 = bv[h * 64 + l31 + 32];
#pragma unroll
    for (int r = 0; r < 16; ++r) {
      v00[r] += bv0; v10[r] += bv0;
      v01[r] += bv1; v11[r] += bv1;
    }
    // write Vt[d][q]: lane's col d is the row; q comes in runs of 4 from regs.
    unsigned short* vtb = VtAll + w * 4096;
#pragma unroll
    for (int td = 0; td < 2; ++td) {
      int d = l31 + 32 * td;
      unsigned short* row = vtb + d * 64;
      int swd = (d & 7) << 3;
#pragma unroll
      for (int tq = 0; tq < 2; ++tq) {
#pragma unroll
        for (int q2 = 0; q2 < 4; ++q2) {
          int qe = 8 * q2 + 4 * hi + 32 * tq;
          uint2 val;
          if (td == 0) {
            const f32x16& t = tq ? v10 : v00;
            val.x = pkbf(t[4 * q2 + 0], t[4 * q2 + 1]);
            val.y = pkbf(t[4 * q2 + 2], t[4 * q2 + 3]);
          } else {
            const f32x16& t = tq ? v11 : v01;
            val.x = pkbf(t[4 * q2 + 0], t[4 * q2 + 1]);
            val.y = pkbf(t[4 * q2 + 2], t[4 * q2 + 3]);
          }
          *reinterpret_cast<uint2*>(row + (qe ^ swd)) = val;
        }
      }
    }
  }

  // ---- S^T = K' Q'^T (rows = key, cols = query) ----
  f32x16 s00 = z16(), s01 = z16(), s10 = z16(), s11 = z16();  // s[tk][tp]
#pragma unroll
  for (int kd = 0; kd < 4; ++kd) {
    s00 = MFMA32(kf[0][kd], qf[0][kd], s00);
    s01 = MFMA32(kf[0][kd], qf[1][kd], s01);
    s10 = MFMA32(kf[1][kd], qf[0][kd], s10);
    s11 = MFMA32(kf[1][kd], qf[1][kd], s11);
  }
  float sinv0 = sm_tp(s00, s10, &Bm[l31][0], hi);
  float sinv1 = sm_tp(s01, s11, &Bm[l31 + 32][0], hi);

  // P frags (unnormalized exp): pf[tp][ks]
  bf16x8 pf[2][4];
  tile2frag(s00, hi, &pf[0][0], &pf[0][1]);
  tile2frag(s10, hi, &pf[0][2], &pf[0][3]);
  tile2frag(s01, hi, &pf[1][0], &pf[1][1]);
  tile2frag(s11, hi, &pf[1][2], &pf[1][3]);

  // ---- R^T = V^T P^T-ish: mfma(A = Vt rows over k, B = P rows over k) ----
  f32x16 r00 = z16(), r01 = z16(), r10 = z16(), r11 = z16();  // r[td][tp]
  {
    const unsigned short* vtb = VtAll + w * 4096;
    const int swd = (l31 & 7) << 3;   // (l31+32)&7 == l31&7
#pragma unroll
    for (int ks = 0; ks < 4; ++ks) {
      int ko = 8 * hi + 16 * ks;
      bf16x8 vt0 = *reinterpret_cast<const bf16x8*>(vtb + l31 * 64 + (ko ^ swd));
      bf16x8 vt1 = *reinterpret_cast<const bf16x8*>(vtb + (l31 + 32) * 64 + (ko ^ swd));
      r00 = MFMA32(vt0, pf[0][ks], r00); r01 = MFMA32(vt0, pf[1][ks], r01);
      r10 = MFMA32(vt1, pf[0][ks], r10); r11 = MFMA32(vt1, pf[1][ks], r11);
    }
  }
#pragma unroll
  for (int r = 0; r < 16; ++r) {
    r00[r] *= sinv0; r10[r] *= sinv0;
    r01[r] *= sinv1; r11[r] *= sinv1;
  }

  __syncthreads();  // all waves done reading Xs; Rs may now overwrite it

  // ---- write Rs[p][h*64+d] (aliases Xs region, same swizzle) ----
#pragma unroll
  for (int tp = 0; tp < 2; ++tp) {
    int p = l31 + 32 * tp;
    unsigned short* row = XsRs + p * 512;
    int swp = (p & 7) << 3;
#pragma unroll
    for (int td = 0; td < 2; ++td) {
#pragma unroll
      for (int q2 = 0; q2 < 4; ++q2) {
        int ce = h * 64 + 32 * td + 8 * q2 + 4 * hi;
        uint2 val;
        if (td == 0) {
          const f32x16& t = tp ? r01 : r00;
          val.x = pkbf(t[4 * q2 + 0], t[4 * q2 + 1]);
          val.y = pkbf(t[4 * q2 + 2], t[4 * q2 + 3]);
        } else {
          const f32x16& t = tp ? r11 : r10;
          val.x = pkbf(t[4 * q2 + 0], t[4 * q2 + 1]);
          val.y = pkbf(t[4 * q2 + 2], t[4 * q2 + 3]);
        }
        *reinterpret_cast<uint2*>(row + (ce ^ swp)) = val;
      }
    }
  }
  __syncthreads();

  // ---- out = Rs @ Wo^T (+bo): wave w owns output cols 64w..64w+63 ----
  f32x16 a00 = z16(), a01 = z16(), a10 = z16(), a11 = z16();  // acc[tp][tc]
  {
    const unsigned short* WoB = Wbf + 786432 + (size_t)(64 * w) * 512;
    const int swp = (l31 & 7) << 3;
#pragma unroll 4
    for (int kc = 0; kc < 32; ++kc) {
      int ko = 8 * hi + 16 * kc;
      bf16x8 ra0 = *reinterpret_cast<const bf16x8*>(XsRs + l31 * 512 + (ko ^ swp));
      bf16x8 ra1 = *reinterpret_cast<const bf16x8*>(XsRs + (l31 + 32) * 512 + (ko ^ swp));
      bf16x8 wo0 = *reinterpret_cast<const bf16x8*>(WoB + (size_t)l31 * 512 + ko);
      bf16x8 wo1 = *reinterpret_cast<const bf16x8*>(WoB + (size_t)(l31 + 32) * 512 + ko);
      a00 = MFMA32(ra0, wo0, a00); a01 = MFMA32(ra0, wo1, a01);
      a10 = MFMA32(ra1, wo0, a10); a11 = MFMA32(ra1, wo1, a11);
    }
  }
  float bo0 = bo[64 * w + l31];
  float bo1 = bo[64 * w + l31 + 32];
  float* og = out + (size_t)bid * 32768;
#pragma unroll
  for (int tp = 0; tp < 2; ++tp) {
#pragma unroll
    for (int r = 0; r < 16; ++r) {
      int p = (r & 3) + 8 * (r >> 2) + 4 * hi + 32 * tp;
      const f32x16& t0 = tp ? a10 : a00;
      const f32x16& t1 = tp ? a11 : a01;
      og[p * 512 + 64 * w + l31] = t0[r] + bo0;
      og[p * 512 + 64 * w + l31 + 32] = t1[r] + bo1;
    }
  }
}

extern "C" void kernel_launch(void* const* d_in, const int* in_sizes, int n_in,
                              void* d_out, int out_size, void* d_ws, size_t ws_size,
                              hipStream_t stream) {
  const float* patches = (const float*)d_in[0];
  const float* Wq = (const float*)d_in[1];
  const float* bq = (const float*)d_in[2];
  const float* Wk = (const float*)d_in[3];
  const float* bk = (const float*)d_in[4];
  const float* Wv = (const float*)d_in[5];
  const float* bv = (const float*)d_in[6];
  const float* Wo = (const float*)d_in[7];
  const float* bo = (const float*)d_in[8];
  const float* posb = (const float*)d_in[9];
  // mask (d_in[10]) / bias_idx (d_in[11],[12]) recomputed on device.
  unsigned short* wbf = (unsigned short*)d_ws;   // 2 MiB
  hipLaunchKernelGGL(prep_weights, dim3(1024), dim3(256), 0, stream, Wq, Wk, Wv, Wo, wbf);
  hipLaunchKernelGGL(swin_fused, dim3(2048), dim3(512), 0, stream,
                     patches, bq, bk, bv, bo, posb, wbf, (float*)d_out);
}

// Round 4
// 540.627 us; speedup vs baseline: 2.5678x; 1.1115x over previous
//
#include <hip/hip_runtime.h>
#include <hip/hip_bf16.h>

typedef __attribute__((ext_vector_type(8))) short bf16x8;
typedef __attribute__((ext_vector_type(16))) float f32x16;
typedef __attribute__((ext_vector_type(4))) unsigned int u32x4;

#define MFMA32(a, b, c) __builtin_amdgcn_mfma_f32_32x32x16_bf16((a), (b), (c), 0, 0, 0)

static __device__ __forceinline__ unsigned int pkbf(float lo, float hi) {
  unsigned int r;
  asm("v_cvt_pk_bf16_f32 %0, %1, %2" : "=v"(r) : "v"(lo), "v"(hi));
  return r;
}

static __device__ __forceinline__ bf16x8 u4_to_bf8(u32x4 u) {
  union { u32x4 u; bf16x8 b; } cv;
  cv.u = u;
  return cv.b;
}

static __device__ __forceinline__ f32x16 z16() {
  f32x16 z;
#pragma unroll
  for (int i = 0; i < 16; ++i) z[i] = 0.0f;
  return z;
}

// Convert one 32x32 MFMA C-tile (value at [row=(r&3)+8*(r>>2)+4*hi][col=lane&31])
// into two bf16 frags with k-runs taken from the ROW dim: f0 = rows 8*hi+{0..7},
// f1 = rows 16+8*hi+{0..7}, column (lane&31) preserved. Result usable directly as
// an MFMA A- or B-operand representing tile^T[l31][row-runs].
static __device__ __forceinline__ void tile2frag(const f32x16 t, int hi,
                                                 bf16x8* f0, bf16x8* f1) {
  unsigned int a0 = pkbf(t[0], t[1]), a1 = pkbf(t[2], t[3]);
  unsigned int b0 = pkbf(t[4], t[5]), b1 = pkbf(t[6], t[7]);
  unsigned int c0 = pkbf(t[8], t[9]), c1 = pkbf(t[10], t[11]);
  unsigned int d0 = pkbf(t[12], t[13]), d1 = pkbf(t[14], t[15]);
  unsigned int sa0 = __shfl_xor((int)a0, 32), sa1 = __shfl_xor((int)a1, 32);
  unsigned int sb0 = __shfl_xor((int)b0, 32), sb1 = __shfl_xor((int)b1, 32);
  unsigned int sc0 = __shfl_xor((int)c0, 32), sc1 = __shfl_xor((int)c1, 32);
  unsigned int sd0 = __shfl_xor((int)d0, 32), sd1 = __shfl_xor((int)d1, 32);
  u32x4 fa, fb;
  fa[0] = hi ? sb0 : a0; fa[1] = hi ? sb1 : a1;
  fa[2] = hi ? b0 : sa0; fa[3] = hi ? b1 : sa1;
  fb[0] = hi ? sd0 : c0; fb[1] = hi ? sd1 : c1;
  fb[2] = hi ? d0 : sc0; fb[3] = hi ? d1 : sc1;
  *f0 = u4_to_bf8(fa);
  *f1 = u4_to_bf8(fb);
}

// T = (X @ Wg^T + bg)^T via mfma(A=W-frags, B=X rows): C rows = d, cols = token.
// Wg is PRE-PACKED in frag order: cell (td, ke, lane) * 8 shorts.
static __device__ __forceinline__ void projT(
    const unsigned short* __restrict__ Wg, const float* __restrict__ bg,
    const unsigned short* Xs, int lane, int l31, int hi, bf16x8 frag[2][4]) {
  f32x16 c00 = z16(), c01 = z16(), c10 = z16(), c11 = z16();  // c[td][tq]
  const int sw = l31 << 3;
  const unsigned short* xr0 = Xs + l31 * 512;
  const unsigned short* xr1 = Xs + (l31 + 32) * 512;
  const unsigned short* wp = Wg + lane * 8;
#pragma unroll 2
  for (int ke = 0; ke < 32; ++ke) {
    const int eo = 8 * hi + 16 * ke;
    bf16x8 x0 = *reinterpret_cast<const bf16x8*>(xr0 + (eo ^ sw));
    bf16x8 x1 = *reinterpret_cast<const bf16x8*>(xr1 + (eo ^ sw));
    bf16x8 w0 = *reinterpret_cast<const bf16x8*>(wp + ke * 512);
    bf16x8 w1 = *reinterpret_cast<const bf16x8*>(wp + 16384 + ke * 512);
    c00 = MFMA32(w0, x0, c00); c01 = MFMA32(w0, x1, c01);
    c10 = MFMA32(w1, x0, c10); c11 = MFMA32(w1, x1, c11);
  }
#pragma unroll
  for (int q2 = 0; q2 < 4; ++q2) {
    float4 b0 = *reinterpret_cast<const float4*>(bg + 8 * q2 + 4 * hi);
    float4 b1 = *reinterpret_cast<const float4*>(bg + 32 + 8 * q2 + 4 * hi);
    c00[4 * q2 + 0] += b0.x; c00[4 * q2 + 1] += b0.y;
    c00[4 * q2 + 2] += b0.z; c00[4 * q2 + 3] += b0.w;
    c01[4 * q2 + 0] += b0.x; c01[4 * q2 + 1] += b0.y;
    c01[4 * q2 + 2] += b0.z; c01[4 * q2 + 3] += b0.w;
    c10[4 * q2 + 0] += b1.x; c10[4 * q2 + 1] += b1.y;
    c10[4 * q2 + 2] += b1.z; c10[4 * q2 + 3] += b1.w;
    c11[4 * q2 + 0] += b1.x; c11[4 * q2 + 1] += b1.y;
    c11[4 * q2 + 2] += b1.z; c11[4 * q2 + 3] += b1.w;
  }
  tile2frag(c00, hi, &frag[0][0], &frag[0][1]);
  tile2frag(c10, hi, &frag[0][2], &frag[0][3]);
  tile2frag(c01, hi, &frag[1][0], &frag[1][1]);
  tile2frag(c11, hi, &frag[1][2], &frag[1][3]);
}

// Scale + bias/mask + softmax for one query tile. A lane holds only HALF the keys
// (hi-interleaved rows); lane l^32 holds the complement -> combine via shfl_xor(32).
static __device__ __forceinline__ float sm_tp(f32x16& t0, f32x16& t1,
                                              const float* BmRow, int swz, int hi) {
#pragma unroll
  for (int q2 = 0; q2 < 4; ++q2) {
    float4 b0 = *reinterpret_cast<const float4*>(BmRow + ((8 * q2 + 4 * hi) ^ swz));
    float4 b1 = *reinterpret_cast<const float4*>(BmRow + ((32 + 8 * q2 + 4 * hi) ^ swz));
    t0[4 * q2 + 0] = fmaf(t0[4 * q2 + 0], 0.125f, b0.x);
    t0[4 * q2 + 1] = fmaf(t0[4 * q2 + 1], 0.125f, b0.y);
    t0[4 * q2 + 2] = fmaf(t0[4 * q2 + 2], 0.125f, b0.z);
    t0[4 * q2 + 3] = fmaf(t0[4 * q2 + 3], 0.125f, b0.w);
    t1[4 * q2 + 0] = fmaf(t1[4 * q2 + 0], 0.125f, b1.x);
    t1[4 * q2 + 1] = fmaf(t1[4 * q2 + 1], 0.125f, b1.y);
    t1[4 * q2 + 2] = fmaf(t1[4 * q2 + 2], 0.125f, b1.z);
    t1[4 * q2 + 3] = fmaf(t1[4 * q2 + 3], 0.125f, b1.w);
  }
  float mx = t0[0];
#pragma unroll
  for (int r = 1; r < 16; ++r) mx = fmaxf(mx, t0[r]);
#pragma unroll
  for (int r = 0; r < 16; ++r) mx = fmaxf(mx, t1[r]);
  mx = fmaxf(mx, __shfl_xor(mx, 32));
  float sum = 0.f;
#pragma unroll
  for (int r = 0; r < 16; ++r) { t0[r] = __expf(t0[r] - mx); sum += t0[r]; }
#pragma unroll
  for (int r = 0; r < 16; ++r) { t1[r] = __expf(t1[r] - mx); sum += t1[r]; }
  sum += __shfl_xor(sum, 32);
  return 1.0f / sum;
}

// Pack fp32 weights -> bf16 frag-order: 32 blocks of [64][512] (Wq h0-7, Wk h0-7,
// Wv h0-7, Wo w0-7); within block, cell (td,ke,lane)*8 = W[32*td+l31][16*ke+8*hi+{0..7}].
__global__ __launch_bounds__(256) void prep_weights(
    const float* __restrict__ Wq, const float* __restrict__ Wk,
    const float* __restrict__ Wv, const float* __restrict__ Wo,
    unsigned short* __restrict__ dst) {
  int i = blockIdx.x * 256 + threadIdx.x;   // 131072 cells x 8 elems
  int blk = i >> 12;
  int c = i & 4095;
  int td = c >> 11;
  int ke = (c >> 6) & 31;
  int lane = c & 63;
  int hi = lane >> 5, l31 = lane & 31;
  int row = 32 * td + l31;
  int e = 16 * ke + 8 * hi;
  int seg = blk >> 3, sub = blk & 7;
  const float* base = (seg == 0) ? Wq : (seg == 1) ? Wk : (seg == 2) ? Wv : Wo;
  const float* src = base + (size_t)(sub * 64 + row) * 512 + e;
  float4 v0 = reinterpret_cast<const float4*>(src)[0];
  float4 v1 = reinterpret_cast<const float4*>(src)[1];
  u32x4 o;
  o[0] = pkbf(v0.x, v0.y); o[1] = pkbf(v0.z, v0.w);
  o[2] = pkbf(v1.x, v1.y); o[3] = pkbf(v1.z, v1.w);
  *reinterpret_cast<u32x4*>(dst + (size_t)blk * 32768 + c * 8) = o;
}

// One block per window (2048 blocks), 512 threads = 8 waves, wave w = head w.
// LDS = 64 KiB (XsRs) + 16 KiB (Bm) = 80 KiB -> 2 blocks/CU.
__global__ __launch_bounds__(512, 4) void swin_fused(
    const float* __restrict__ patches,
    const float* __restrict__ bq, const float* __restrict__ bk,
    const float* __restrict__ bv, const float* __restrict__ bo,
    const float* __restrict__ posb,
    const unsigned short* __restrict__ Wbf,
    float* __restrict__ out) {
  __shared__ unsigned short XsRs[64 * 512];  // X bf16, swizzled; later aliased by Rs
  __shared__ float Bm[64 * 64];              // bias+mask, granule-swizzled

  const int tid = threadIdx.x;
  const int bid = blockIdx.x;                // ((b*16+y)*16+x)
  const int wxi = bid & 15;
  const int wyi = (bid >> 4) & 15;
  const int w = tid >> 6;
  const int lane = tid & 63;
  const int l31 = lane & 31;
  const int hi = lane >> 5;
  const int h = w;

  // ---- Phase A: stage X (fp32->bf16, 5-bit granule swizzle) + build Bm ----
  const float* Xg = patches + (size_t)bid * 32768;
#pragma unroll
  for (int it = 0; it < 8; ++it) {
    int p = it * 8 + w;
    int e0 = lane << 3;
    const float4* gp = reinterpret_cast<const float4*>(Xg + p * 512 + e0);
    float4 v0 = gp[0], v1 = gp[1];
    u32x4 xv;
    xv[0] = pkbf(v0.x, v0.y); xv[1] = pkbf(v0.z, v0.w);
    xv[2] = pkbf(v1.x, v1.y); xv[3] = pkbf(v1.z, v1.w);
    *reinterpret_cast<u32x4*>(XsRs + p * 512 + (e0 ^ ((p & 31) << 3))) = xv;
  }
#pragma unroll
  for (int ii = 0; ii < 8; ++ii) {
    int i = ii * 512 + tid;
    int p = i >> 6, k = i & 63;
    int pr = p >> 3, pc = p & 7, kr = k >> 3, kc = k & 7;
    float b = posb[(pr - kr + 7) * 15 + (pc - kc + 7)];
    bool mk = ((wyi == 15) && ((pr < 4) != (kr < 4))) ||
              ((wxi == 15) && ((pc < 4) != (kc < 4)));
    Bm[p * 64 + (k ^ ((p & 15) << 2))] = mk ? -1e30f : b;
  }
  __syncthreads();

  // ---- Per-wave head pipeline: K, Q projections ----
  bf16x8 kf[2][4], qf[2][4];
  projT(Wbf + (size_t)(8 + h) * 32768, bk + h * 64, XsRs, lane, l31, hi, kf);
  projT(Wbf + (size_t)(0 + h) * 32768, bq + h * 64, XsRs, lane, l31, hi, qf);

  // ---- V = X @ Wv^T + bv; A-frags for PV straight from C-tiles (no LDS) ----
  bf16x8 vf[2][4];  // vf[td][ks] = V^T[d=l31(+32td)][q-run 16*ks+8*hi+{0..7}]
  {
    f32x16 v00 = z16(), v01 = z16(), v10 = z16(), v11 = z16();  // v[tq][td]
    const int sw = l31 << 3;
    const unsigned short* xr0 = XsRs + l31 * 512;
    const unsigned short* xr1 = XsRs + (l31 + 32) * 512;
    const unsigned short* wp = Wbf + (size_t)(16 + h) * 32768 + lane * 8;
#pragma unroll 2
    for (int ke = 0; ke < 32; ++ke) {
      const int eo = 8 * hi + 16 * ke;
      bf16x8 x0 = *reinterpret_cast<const bf16x8*>(xr0 + (eo ^ sw));
      bf16x8 x1 = *reinterpret_cast<const bf16x8*>(xr1 + (eo ^ sw));
      bf16x8 w0 = *reinterpret_cast<const bf16x8*>(wp + ke * 512);
      bf16x8 w1 = *reinterpret_cast<const bf16x8*>(wp + 16384 + ke * 512);
      v00 = MFMA32(x0, w0, v00); v01 = MFMA32(x0, w1, v01);
      v10 = MFMA32(x1, w0, v10); v11 = MFMA32(x1, w1, v11);
    }
    float bv0 = bv[h * 64 + l31];
    float bv1 = bv[h * 64 + l31 + 32];
#pragma unroll
    for (int r = 0; r < 16; ++r) {
      v00[r] += bv0; v10[r] += bv0;
      v01[r] += bv1; v11[r] += bv1;
    }
    tile2frag(v00, hi, &vf[0][0], &vf[0][1]);
    tile2frag(v10, hi, &vf[0][2], &vf[0][3]);
    tile2frag(v01, hi, &vf[1][0], &vf[1][1]);
    tile2frag(v11, hi, &vf[1][2], &vf[1][3]);
  }

  // ---- S^T = K' Q'^T (rows = key, cols = query) ----
  f32x16 s00 = z16(), s01 = z16(), s10 = z16(), s11 = z16();  // s[tk][tp]
#pragma unroll
  for (int kd = 0; kd < 4; ++kd) {
    s00 = MFMA32(kf[0][kd], qf[0][kd], s00);
    s01 = MFMA32(kf[0][kd], qf[1][kd], s01);
    s10 = MFMA32(kf[1][kd], qf[0][kd], s10);
    s11 = MFMA32(kf[1][kd], qf[1][kd], s11);
  }
  const int bswz = (l31 & 15) << 2;
  float sinv0 = sm_tp(s00, s10, Bm + l31 * 64, bswz, hi);
  float sinv1 = sm_tp(s01, s11, Bm + (l31 + 32) * 64, bswz, hi);

  // P frags (unnormalized exp): pf[tp][ks]
  bf16x8 pf[2][4];
  tile2frag(s00, hi, &pf[0][0], &pf[0][1]);
  tile2frag(s10, hi, &pf[0][2], &pf[0][3]);
  tile2frag(s01, hi, &pf[1][0], &pf[1][1]);
  tile2frag(s11, hi, &pf[1][2], &pf[1][3]);

  // ---- R^T = V^T @ P: all-register MFMA ----
  f32x16 r00 = z16(), r01 = z16(), r10 = z16(), r11 = z16();  // r[td][tp]
#pragma unroll
  for (int ks = 0; ks < 4; ++ks) {
    r00 = MFMA32(vf[0][ks], pf[0][ks], r00); r01 = MFMA32(vf[0][ks], pf[1][ks], r01);
    r10 = MFMA32(vf[1][ks], pf[0][ks], r10); r11 = MFMA32(vf[1][ks], pf[1][ks], r11);
  }
#pragma unroll
  for (int r = 0; r < 16; ++r) {
    r00[r] *= sinv0; r10[r] *= sinv0;
    r01[r] *= sinv1; r11[r] *= sinv1;
  }

  __syncthreads();  // all waves done reading Xs; Rs may now overwrite it

  // ---- write Rs[p][h*64+d] (aliases Xs, same 5-bit swizzle) ----
#pragma unroll
  for (int tp = 0; tp < 2; ++tp) {
    int p = l31 + 32 * tp;
    unsigned short* row = XsRs + p * 512;
    int swp = l31 << 3;   // (p & 31) << 3
#pragma unroll
    for (int td = 0; td < 2; ++td) {
#pragma unroll
      for (int q2 = 0; q2 < 4; ++q2) {
        int ce = h * 64 + 32 * td + 8 * q2 + 4 * hi;
        uint2 val;
        if (td == 0) {
          const f32x16& t = tp ? r01 : r00;
          val.x = pkbf(t[4 * q2 + 0], t[4 * q2 + 1]);
          val.y = pkbf(t[4 * q2 + 2], t[4 * q2 + 3]);
        } else {
          const f32x16& t = tp ? r11 : r10;
          val.x = pkbf(t[4 * q2 + 0], t[4 * q2 + 1]);
          val.y = pkbf(t[4 * q2 + 2], t[4 * q2 + 3]);
        }
        *reinterpret_cast<uint2*>(row + (ce ^ swp)) = val;
      }
    }
  }
  __syncthreads();

  // ---- out = Rs @ Wo^T (+bo): wave w owns output cols 64w..64w+63 ----
  f32x16 a00 = z16(), a01 = z16(), a10 = z16(), a11 = z16();  // acc[tp][tc]
  {
    const unsigned short* wp = Wbf + (size_t)(24 + w) * 32768 + lane * 8;
    const int swp = l31 << 3;
#pragma unroll 2
    for (int kc = 0; kc < 32; ++kc) {
      int ko = 8 * hi + 16 * kc;
      bf16x8 ra0 = *reinterpret_cast<const bf16x8*>(XsRs + l31 * 512 + (ko ^ swp));
      bf16x8 ra1 = *reinterpret_cast<const bf16x8*>(XsRs + (l31 + 32) * 512 + (ko ^ swp));
      bf16x8 wo0 = *reinterpret_cast<const bf16x8*>(wp + kc * 512);
      bf16x8 wo1 = *reinterpret_cast<const bf16x8*>(wp + 16384 + kc * 512);
      a00 = MFMA32(ra0, wo0, a00); a01 = MFMA32(ra0, wo1, a01);
      a10 = MFMA32(ra1, wo0, a10); a11 = MFMA32(ra1, wo1, a11);
    }
  }
  float bo0 = bo[64 * w + l31];
  float bo1 = bo[64 * w + l31 + 32];
  float* og = out + (size_t)bid * 32768;
#pragma unroll
  for (int tp = 0; tp < 2; ++tp) {
#pragma unroll
    for (int r = 0; r < 16; ++r) {
      int p = (r & 3) + 8 * (r >> 2) + 4 * hi + 32 * tp;
      const f32x16& t0 = tp ? a10 : a00;
      const f32x16& t1 = tp ? a11 : a01;
      og[p * 512 + 64 * w + l31] = t0[r] + bo0;
      og[p * 512 + 64 * w + l31 + 32] = t1[r] + bo1;
    }
  }
}

extern "C" void kernel_launch(void* const* d_in, const int* in_sizes, int n_in,
                              void* d_out, int out_size, void* d_ws, size_t ws_size,
                              hipStream_t stream) {
  const float* patches = (const float*)d_in[0];
  const float* Wq = (const float*)d_in[1];
  const float* bq = (const float*)d_in[2];
  const float* Wk = (const float*)d_in[3];
  const float* bk = (const float*)d_in[4];
  const float* Wv = (const float*)d_in[5];
  const float* bv = (const float*)d_in[6];
  const float* Wo = (const float*)d_in[7];
  const float* bo = (const float*)d_in[8];
  const float* posb = (const float*)d_in[9];
  // mask (d_in[10]) / bias_idx (d_in[11],[12]) recomputed on device.
  unsigned short* wbf = (unsigned short*)d_ws;   // 2 MiB
  hipLaunchKernelGGL(prep_weights, dim3(512), dim3(256), 0, stream, Wq, Wk, Wv, Wo, wbf);
  hipLaunchKernelGGL(swin_fused, dim3(2048), dim3(512), 0, stream,
                     patches, bq, bk, bv, bo, posb, wbf, (float*)d_out);
}

// Round 5
// 435.106 us; speedup vs baseline: 3.1905x; 1.2425x over previous
//
#include <hip/hip_runtime.h>
#include <hip/hip_bf16.h>

typedef __attribute__((ext_vector_type(8))) short bf16x8;
typedef __attribute__((ext_vector_type(16))) float f32x16;
typedef __attribute__((ext_vector_type(4))) unsigned int u32x4;

#define MFMA32(a, b, c) __builtin_amdgcn_mfma_f32_32x32x16_bf16((a), (b), (c), 0, 0, 0)

static __device__ __forceinline__ unsigned int pkbf(float lo, float hi) {
  unsigned int r;
  asm("v_cvt_pk_bf16_f32 %0, %1, %2" : "=v"(r) : "v"(lo), "v"(hi));
  return r;
}

static __device__ __forceinline__ bf16x8 u4_to_bf8(u32x4 u) {
  union { u32x4 u; bf16x8 b; } cv;
  cv.u = u;
  return cv.b;
}

static __device__ __forceinline__ f32x16 z16() {
  f32x16 z;
#pragma unroll
  for (int i = 0; i < 16; ++i) z[i] = 0.0f;
  return z;
}

// Convert one 32x32 MFMA C-tile (value at [row=(r&3)+8*(r>>2)+4*hi][col=lane&31])
// into two bf16 frags with k-runs taken from the ROW dim: f0 = rows 8*hi+{0..7},
// f1 = rows 16+8*hi+{0..7}, column (lane&31) preserved.
static __device__ __forceinline__ void tile2frag(const f32x16 t, int hi,
                                                 bf16x8* f0, bf16x8* f1) {
  unsigned int a0 = pkbf(t[0], t[1]), a1 = pkbf(t[2], t[3]);
  unsigned int b0 = pkbf(t[4], t[5]), b1 = pkbf(t[6], t[7]);
  unsigned int c0 = pkbf(t[8], t[9]), c1 = pkbf(t[10], t[11]);
  unsigned int d0 = pkbf(t[12], t[13]), d1 = pkbf(t[14], t[15]);
  unsigned int sa0 = __shfl_xor((int)a0, 32), sa1 = __shfl_xor((int)a1, 32);
  unsigned int sb0 = __shfl_xor((int)b0, 32), sb1 = __shfl_xor((int)b1, 32);
  unsigned int sc0 = __shfl_xor((int)c0, 32), sc1 = __shfl_xor((int)c1, 32);
  unsigned int sd0 = __shfl_xor((int)d0, 32), sd1 = __shfl_xor((int)d1, 32);
  u32x4 fa, fb;
  fa[0] = hi ? sb0 : a0; fa[1] = hi ? sb1 : a1;
  fa[2] = hi ? b0 : sa0; fa[3] = hi ? b1 : sa1;
  fb[0] = hi ? sd0 : c0; fb[1] = hi ? sd1 : c1;
  fb[2] = hi ? d0 : sc0; fb[3] = hi ? d1 : sc1;
  *f0 = u4_to_bf8(fa);
  *f1 = u4_to_bf8(fb);
}

// T = (X @ Wg^T + bg)^T via mfma(A=W-frags, B=X rows), SEQUENTIAL over td so only
// 2 C-tiles (32 regs) are live at a time. Wg pre-packed: cell (td,ke,lane)*8.
static __device__ __forceinline__ void projT(
    const unsigned short* __restrict__ Wg, const float* __restrict__ bg,
    const unsigned short* Xs, int lane, int l31, int hi, bf16x8 frag[2][4]) {
  const int sw = l31 << 3;
  const unsigned short* xr0 = Xs + l31 * 512;
  const unsigned short* xr1 = Xs + (l31 + 32) * 512;
#pragma unroll
  for (int td = 0; td < 2; ++td) {
    f32x16 c0 = z16(), c1 = z16();   // c[tq] for this td
    const unsigned short* wp = Wg + td * 16384 + lane * 8;
#pragma unroll 2
    for (int ke = 0; ke < 32; ++ke) {
      const int eo = 8 * hi + 16 * ke;
      bf16x8 x0 = *reinterpret_cast<const bf16x8*>(xr0 + (eo ^ sw));
      bf16x8 x1 = *reinterpret_cast<const bf16x8*>(xr1 + (eo ^ sw));
      bf16x8 w0 = *reinterpret_cast<const bf16x8*>(wp + ke * 512);
      c0 = MFMA32(w0, x0, c0);
      c1 = MFMA32(w0, x1, c1);
    }
    const float* bb = bg + 32 * td;
#pragma unroll
    for (int q2 = 0; q2 < 4; ++q2) {
      float4 b0 = *reinterpret_cast<const float4*>(bb + 8 * q2 + 4 * hi);
      c0[4 * q2 + 0] += b0.x; c0[4 * q2 + 1] += b0.y;
      c0[4 * q2 + 2] += b0.z; c0[4 * q2 + 3] += b0.w;
      c1[4 * q2 + 0] += b0.x; c1[4 * q2 + 1] += b0.y;
      c1[4 * q2 + 2] += b0.z; c1[4 * q2 + 3] += b0.w;
    }
    tile2frag(c0, hi, &frag[0][2 * td], &frag[0][2 * td + 1]);
    tile2frag(c1, hi, &frag[1][2 * td], &frag[1][2 * td + 1]);
  }
}

// Scale + bias/mask + softmax for one query tile. A lane holds only HALF the keys
// (hi-interleaved rows); lane l^32 holds the complement -> combine via shfl_xor(32).
static __device__ __forceinline__ float sm_tp(f32x16& t0, f32x16& t1,
                                              const float* BmRow, int swz, int hi) {
#pragma unroll
  for (int q2 = 0; q2 < 4; ++q2) {
    float4 b0 = *reinterpret_cast<const float4*>(BmRow + ((8 * q2 + 4 * hi) ^ swz));
    float4 b1 = *reinterpret_cast<const float4*>(BmRow + ((32 + 8 * q2 + 4 * hi) ^ swz));
    t0[4 * q2 + 0] = fmaf(t0[4 * q2 + 0], 0.125f, b0.x);
    t0[4 * q2 + 1] = fmaf(t0[4 * q2 + 1], 0.125f, b0.y);
    t0[4 * q2 + 2] = fmaf(t0[4 * q2 + 2], 0.125f, b0.z);
    t0[4 * q2 + 3] = fmaf(t0[4 * q2 + 3], 0.125f, b0.w);
    t1[4 * q2 + 0] = fmaf(t1[4 * q2 + 0], 0.125f, b1.x);
    t1[4 * q2 + 1] = fmaf(t1[4 * q2 + 1], 0.125f, b1.y);
    t1[4 * q2 + 2] = fmaf(t1[4 * q2 + 2], 0.125f, b1.z);
    t1[4 * q2 + 3] = fmaf(t1[4 * q2 + 3], 0.125f, b1.w);
  }
  float mx = t0[0];
#pragma unroll
  for (int r = 1; r < 16; ++r) mx = fmaxf(mx, t0[r]);
#pragma unroll
  for (int r = 0; r < 16; ++r) mx = fmaxf(mx, t1[r]);
  mx = fmaxf(mx, __shfl_xor(mx, 32));
  float sum = 0.f;
#pragma unroll
  for (int r = 0; r < 16; ++r) { t0[r] = __expf(t0[r] - mx); sum += t0[r]; }
#pragma unroll
  for (int r = 0; r < 16; ++r) { t1[r] = __expf(t1[r] - mx); sum += t1[r]; }
  sum += __shfl_xor(sum, 32);
  return 1.0f / sum;
}

// Pack fp32 weights -> bf16 frag-order: 32 blocks of [64][512] (Wq h0-7, Wk h0-7,
// Wv h0-7, Wo w0-7); cell (td,ke,lane)*8 = W[32*td+l31][16*ke+8*hi+{0..7}].
__global__ __launch_bounds__(256) void prep_weights(
    const float* __restrict__ Wq, const float* __restrict__ Wk,
    const float* __restrict__ Wv, const float* __restrict__ Wo,
    unsigned short* __restrict__ dst) {
  int i = blockIdx.x * 256 + threadIdx.x;   // 131072 cells x 8 elems
  int blk = i >> 12;
  int c = i & 4095;
  int td = c >> 11;
  int ke = (c >> 6) & 31;
  int lane = c & 63;
  int hi = lane >> 5, l31 = lane & 31;
  int row = 32 * td + l31;
  int e = 16 * ke + 8 * hi;
  int seg = blk >> 3, sub = blk & 7;
  const float* base = (seg == 0) ? Wq : (seg == 1) ? Wk : (seg == 2) ? Wv : Wo;
  const float* src = base + (size_t)(sub * 64 + row) * 512 + e;
  float4 v0 = reinterpret_cast<const float4*>(src)[0];
  float4 v1 = reinterpret_cast<const float4*>(src)[1];
  u32x4 o;
  o[0] = pkbf(v0.x, v0.y); o[1] = pkbf(v0.z, v0.w);
  o[2] = pkbf(v1.x, v1.y); o[3] = pkbf(v1.z, v1.w);
  *reinterpret_cast<u32x4*>(dst + (size_t)blk * 32768 + c * 8) = o;
}

// One block per window (2048 blocks), 512 threads = 8 waves, wave w = head w.
// LDS = 64 KiB (XsRs) + 16 KiB (Bm) = 80 KiB -> 2 blocks/CU, 4 waves/EU.
__global__ __launch_bounds__(512, 4) void swin_fused(
    const float* __restrict__ patches,
    const float* __restrict__ bq, const float* __restrict__ bk,
    const float* __restrict__ bv, const float* __restrict__ bo,
    const float* __restrict__ posb,
    const unsigned short* __restrict__ Wbf,
    float* __restrict__ out) {
  __shared__ unsigned short XsRs[64 * 512];  // X bf16, swizzled; later aliased by Rs
  __shared__ float Bm[64 * 64];              // bias+mask, granule-swizzled

  const int tid = threadIdx.x;
  const int bid = blockIdx.x;                // ((b*16+y)*16+x)
  const int wxi = bid & 15;
  const int wyi = (bid >> 4) & 15;
  const int w = tid >> 6;
  const int lane = tid & 63;
  const int l31 = lane & 31;
  const int hi = lane >> 5;
  const int h = w;

  // ---- Phase A: stage X (fp32->bf16, 5-bit granule swizzle) + build Bm ----
  const float* Xg = patches + (size_t)bid * 32768;
#pragma unroll
  for (int it = 0; it < 8; ++it) {
    int p = it * 8 + w;
    int e0 = lane << 3;
    const float4* gp = reinterpret_cast<const float4*>(Xg + p * 512 + e0);
    float4 v0 = gp[0], v1 = gp[1];
    u32x4 xv;
    xv[0] = pkbf(v0.x, v0.y); xv[1] = pkbf(v0.z, v0.w);
    xv[2] = pkbf(v1.x, v1.y); xv[3] = pkbf(v1.z, v1.w);
    *reinterpret_cast<u32x4*>(XsRs + p * 512 + (e0 ^ ((p & 31) << 3))) = xv;
  }
#pragma unroll
  for (int ii = 0; ii < 8; ++ii) {
    int i = ii * 512 + tid;
    int p = i >> 6, k = i & 63;
    int pr = p >> 3, pc = p & 7, kr = k >> 3, kc = k & 7;
    float b = posb[(pr - kr + 7) * 15 + (pc - kc + 7)];
    bool mk = ((wyi == 15) && ((pr < 4) != (kr < 4))) ||
              ((wxi == 15) && ((pc < 4) != (kc < 4)));
    Bm[p * 64 + (k ^ ((p & 15) << 2))] = mk ? -1e30f : b;
  }
  __syncthreads();

  // ---- K, Q projections (frags in registers) ----
  bf16x8 kf[2][4], qf[2][4];
  projT(Wbf + (size_t)(8 + h) * 32768, bk + h * 64, XsRs, lane, l31, hi, kf);
  projT(Wbf + (size_t)(0 + h) * 32768, bq + h * 64, XsRs, lane, l31, hi, qf);

  // ---- S^T = K' Q'^T + softmax, one query-tile tp at a time ----
  bf16x8 pf[2][4];   // unnormalized exp(P) frags
  float sinv0, sinv1;
  const int bswz = (l31 & 15) << 2;
#pragma unroll
  for (int tp = 0; tp < 2; ++tp) {
    f32x16 s0 = z16(), s1 = z16();   // s[tk] for this tp
#pragma unroll
    for (int kd = 0; kd < 4; ++kd) {
      s0 = MFMA32(kf[0][kd], qf[tp][kd], s0);
      s1 = MFMA32(kf[1][kd], qf[tp][kd], s1);
    }
    float si = sm_tp(s0, s1, Bm + (l31 + 32 * tp) * 64, bswz, hi);
    if (tp == 0) sinv0 = si; else sinv1 = si;
    tile2frag(s0, hi, &pf[tp][0], &pf[tp][1]);
    tile2frag(s1, hi, &pf[tp][2], &pf[tp][3]);
  }

  // ---- V proj fused with PV, one td (output-d tile) at a time ----
  f32x16 r00, r01, r10, r11;   // r[td][tp]
  {
    const int sw = l31 << 3;
    const unsigned short* xr0 = XsRs + l31 * 512;
    const unsigned short* xr1 = XsRs + (l31 + 32) * 512;
#pragma unroll
    for (int td = 0; td < 2; ++td) {
      f32x16 v0 = z16(), v1 = z16();   // v[tq] for this td
      const unsigned short* wp = Wbf + (size_t)(16 + h) * 32768 + td * 16384 + lane * 8;
#pragma unroll 2
      for (int ke = 0; ke < 32; ++ke) {
        const int eo = 8 * hi + 16 * ke;
        bf16x8 x0 = *reinterpret_cast<const bf16x8*>(xr0 + (eo ^ sw));
        bf16x8 x1 = *reinterpret_cast<const bf16x8*>(xr1 + (eo ^ sw));
        bf16x8 w0 = *reinterpret_cast<const bf16x8*>(wp + ke * 512);
        v0 = MFMA32(x0, w0, v0);
        v1 = MFMA32(x1, w0, v1);
      }
      float bvv = bv[h * 64 + 32 * td + l31];
#pragma unroll
      for (int r = 0; r < 16; ++r) { v0[r] += bvv; v1[r] += bvv; }
      bf16x8 vf[4];   // V^T[d=l31+32td][q-run 16*ks+8*hi+{0..7}]
      tile2frag(v0, hi, &vf[0], &vf[1]);
      tile2frag(v1, hi, &vf[2], &vf[3]);
      f32x16 ra = z16(), rb = z16();
#pragma unroll
      for (int ks = 0; ks < 4; ++ks) {
        ra = MFMA32(vf[ks], pf[0][ks], ra);
        rb = MFMA32(vf[ks], pf[1][ks], rb);
      }
      if (td == 0) { r00 = ra; r01 = rb; } else { r10 = ra; r11 = rb; }
    }
  }
#pragma unroll
  for (int r = 0; r < 16; ++r) {
    r00[r] *= sinv0; r10[r] *= sinv0;
    r01[r] *= sinv1; r11[r] *= sinv1;
  }

  __syncthreads();  // all waves done reading Xs; Rs may now overwrite it

  // ---- write Rs[p][h*64+d] (aliases Xs, same 5-bit swizzle) ----
#pragma unroll
  for (int tp = 0; tp < 2; ++tp) {
    int p = l31 + 32 * tp;
    unsigned short* row = XsRs + p * 512;
    int swp = l31 << 3;   // (p & 31) << 3
#pragma unroll
    for (int td = 0; td < 2; ++td) {
#pragma unroll
      for (int q2 = 0; q2 < 4; ++q2) {
        int ce = h * 64 + 32 * td + 8 * q2 + 4 * hi;
        uint2 val;
        if (td == 0) {
          const f32x16& t = tp ? r01 : r00;
          val.x = pkbf(t[4 * q2 + 0], t[4 * q2 + 1]);
          val.y = pkbf(t[4 * q2 + 2], t[4 * q2 + 3]);
        } else {
          const f32x16& t = tp ? r11 : r10;
          val.x = pkbf(t[4 * q2 + 0], t[4 * q2 + 1]);
          val.y = pkbf(t[4 * q2 + 2], t[4 * q2 + 3]);
        }
        *reinterpret_cast<uint2*>(row + (ce ^ swp)) = val;
      }
    }
  }
  __syncthreads();

  // ---- out = Rs @ Wo^T (+bo): wave w owns output cols 64w..64w+63 ----
  f32x16 a00 = z16(), a01 = z16(), a10 = z16(), a11 = z16();  // acc[tp][tc]
  {
    const unsigned short* wp = Wbf + (size_t)(24 + w) * 32768 + lane * 8;
    const int swp = l31 << 3;
#pragma unroll 2
    for (int kc = 0; kc < 32; ++kc) {
      int ko = 8 * hi + 16 * kc;
      bf16x8 ra0 = *reinterpret_cast<const bf16x8*>(XsRs + l31 * 512 + (ko ^ swp));
      bf16x8 ra1 = *reinterpret_cast<const bf16x8*>(XsRs + (l31 + 32) * 512 + (ko ^ swp));
      bf16x8 wo0 = *reinterpret_cast<const bf16x8*>(wp + kc * 512);
      bf16x8 wo1 = *reinterpret_cast<const bf16x8*>(wp + 16384 + kc * 512);
      a00 = MFMA32(ra0, wo0, a00); a01 = MFMA32(ra0, wo1, a01);
      a10 = MFMA32(ra1, wo0, a10); a11 = MFMA32(ra1, wo1, a11);
    }
  }
  float bo0 = bo[64 * w + l31];
  float bo1 = bo[64 * w + l31 + 32];
  float* og = out + (size_t)bid * 32768;
#pragma unroll
  for (int tp = 0; tp < 2; ++tp) {
#pragma unroll
    for (int r = 0; r < 16; ++r) {
      int p = (r & 3) + 8 * (r >> 2) + 4 * hi + 32 * tp;
      const f32x16& t0 = tp ? a10 : a00;
      const f32x16& t1 = tp ? a11 : a01;
      og[p * 512 + 64 * w + l31] = t0[r] + bo0;
      og[p * 512 + 64 * w + l31 + 32] = t1[r] + bo1;
    }
  }
}

extern "C" void kernel_launch(void* const* d_in, const int* in_sizes, int n_in,
                              void* d_out, int out_size, void* d_ws, size_t ws_size,
                              hipStream_t stream) {
  const float* patches = (const float*)d_in[0];
  const float* Wq = (const float*)d_in[1];
  const float* bq = (const float*)d_in[2];
  const float* Wk = (const float*)d_in[3];
  const float* bk = (const float*)d_in[4];
  const float* Wv = (const float*)d_in[5];
  const float* bv = (const float*)d_in[6];
  const float* Wo = (const float*)d_in[7];
  const float* bo = (const float*)d_in[8];
  const float* posb = (const float*)d_in[9];
  // mask (d_in[10]) / bias_idx (d_in[11],[12]) recomputed on device.
  unsigned short* wbf = (unsigned short*)d_ws;   // 2 MiB
  hipLaunchKernelGGL(prep_weights, dim3(512), dim3(256), 0, stream, Wq, Wk, Wv, Wo, wbf);
  hipLaunchKernelGGL(swin_fused, dim3(2048), dim3(512), 0, stream,
                     patches, bq, bk, bv, bo, posb, wbf, (float*)d_out);
}

// Round 6
// 431.773 us; speedup vs baseline: 3.2152x; 1.0077x over previous
//
#include <hip/hip_runtime.h>
#include <hip/hip_bf16.h>

typedef __attribute__((ext_vector_type(8))) short bf16x8;
typedef __attribute__((ext_vector_type(16))) float f32x16;
typedef __attribute__((ext_vector_type(4))) unsigned int u32x4;

#define MFMA32(a, b, c) __builtin_amdgcn_mfma_f32_32x32x16_bf16((a), (b), (c), 0, 0, 0)

static __device__ __forceinline__ unsigned int pkbf(float lo, float hi) {
  unsigned int r;
  asm("v_cvt_pk_bf16_f32 %0, %1, %2" : "=v"(r) : "v"(lo), "v"(hi));
  return r;
}

static __device__ __forceinline__ bf16x8 u4_to_bf8(u32x4 u) {
  union { u32x4 u; bf16x8 b; } cv;
  cv.u = u;
  return cv.b;
}

static __device__ __forceinline__ f32x16 z16() {
  f32x16 z;
#pragma unroll
  for (int i = 0; i < 16; ++i) z[i] = 0.0f;
  return z;
}

// Convert one 32x32 MFMA C-tile (value at [row=(r&3)+8*(r>>2)+4*hi][col=lane&31])
// into two bf16 frags with k-runs taken from the ROW dim: f0 = rows 8*hi+{0..7},
// f1 = rows 16+8*hi+{0..7}, column (lane&31) preserved.
static __device__ __forceinline__ void tile2frag(const f32x16 t, int hi,
                                                 bf16x8* f0, bf16x8* f1) {
  unsigned int a0 = pkbf(t[0], t[1]), a1 = pkbf(t[2], t[3]);
  unsigned int b0 = pkbf(t[4], t[5]), b1 = pkbf(t[6], t[7]);
  unsigned int c0 = pkbf(t[8], t[9]), c1 = pkbf(t[10], t[11]);
  unsigned int d0 = pkbf(t[12], t[13]), d1 = pkbf(t[14], t[15]);
  unsigned int sa0 = __shfl_xor((int)a0, 32), sa1 = __shfl_xor((int)a1, 32);
  unsigned int sb0 = __shfl_xor((int)b0, 32), sb1 = __shfl_xor((int)b1, 32);
  unsigned int sc0 = __shfl_xor((int)c0, 32), sc1 = __shfl_xor((int)c1, 32);
  unsigned int sd0 = __shfl_xor((int)d0, 32), sd1 = __shfl_xor((int)d1, 32);
  u32x4 fa, fb;
  fa[0] = hi ? sb0 : a0; fa[1] = hi ? sb1 : a1;
  fa[2] = hi ? b0 : sa0; fa[3] = hi ? b1 : sa1;
  fb[0] = hi ? sd0 : c0; fb[1] = hi ? sd1 : c1;
  fb[2] = hi ? d0 : sc0; fb[3] = hi ? d1 : sc1;
  *f0 = u4_to_bf8(fa);
  *f1 = u4_to_bf8(fb);
}

// T = (X @ Wg^T + bg)^T via mfma(A=W-frags, B=X rows), SEQUENTIAL over td so only
// 2 C-tiles (32 regs) are live at a time. Wg pre-packed: cell (td,ke,lane)*8.
static __device__ __forceinline__ void projT(
    const unsigned short* __restrict__ Wg, const float* __restrict__ bg,
    const unsigned short* Xs, int lane, int l31, int hi, bf16x8 frag[2][4]) {
  const int sw = l31 << 3;
  const unsigned short* xr0 = Xs + l31 * 512;
  const unsigned short* xr1 = Xs + (l31 + 32) * 512;
#pragma unroll
  for (int td = 0; td < 2; ++td) {
    f32x16 c0 = z16(), c1 = z16();   // c[tq] for this td
    const unsigned short* wp = Wg + td * 16384 + lane * 8;
#pragma unroll 2
    for (int ke = 0; ke < 32; ++ke) {
      const int eo = 8 * hi + 16 * ke;
      bf16x8 x0 = *reinterpret_cast<const bf16x8*>(xr0 + (eo ^ sw));
      bf16x8 x1 = *reinterpret_cast<const bf16x8*>(xr1 + (eo ^ sw));
      bf16x8 w0 = *reinterpret_cast<const bf16x8*>(wp + ke * 512);
      c0 = MFMA32(w0, x0, c0);
      c1 = MFMA32(w0, x1, c1);
    }
    const float* bb = bg + 32 * td;
#pragma unroll
    for (int q2 = 0; q2 < 4; ++q2) {
      float4 b0 = *reinterpret_cast<const float4*>(bb + 8 * q2 + 4 * hi);
      c0[4 * q2 + 0] += b0.x; c0[4 * q2 + 1] += b0.y;
      c0[4 * q2 + 2] += b0.z; c0[4 * q2 + 3] += b0.w;
      c1[4 * q2 + 0] += b0.x; c1[4 * q2 + 1] += b0.y;
      c1[4 * q2 + 2] += b0.z; c1[4 * q2 + 3] += b0.w;
    }
    tile2frag(c0, hi, &frag[0][2 * td], &frag[0][2 * td + 1]);
    tile2frag(c1, hi, &frag[1][2 * td], &frag[1][2 * td + 1]);
  }
}

// Scale + bias/mask + softmax for one query tile. A lane holds only HALF the keys
// (hi-interleaved rows); lane l^32 holds the complement -> combine via shfl_xor(32).
static __device__ __forceinline__ float sm_tp(f32x16& t0, f32x16& t1,
                                              const float* BmRow, int swz, int hi) {
#pragma unroll
  for (int q2 = 0; q2 < 4; ++q2) {
    float4 b0 = *reinterpret_cast<const float4*>(BmRow + ((8 * q2 + 4 * hi) ^ swz));
    float4 b1 = *reinterpret_cast<const float4*>(BmRow + ((32 + 8 * q2 + 4 * hi) ^ swz));
    t0[4 * q2 + 0] = fmaf(t0[4 * q2 + 0], 0.125f, b0.x);
    t0[4 * q2 + 1] = fmaf(t0[4 * q2 + 1], 0.125f, b0.y);
    t0[4 * q2 + 2] = fmaf(t0[4 * q2 + 2], 0.125f, b0.z);
    t0[4 * q2 + 3] = fmaf(t0[4 * q2 + 3], 0.125f, b0.w);
    t1[4 * q2 + 0] = fmaf(t1[4 * q2 + 0], 0.125f, b1.x);
    t1[4 * q2 + 1] = fmaf(t1[4 * q2 + 1], 0.125f, b1.y);
    t1[4 * q2 + 2] = fmaf(t1[4 * q2 + 2], 0.125f, b1.z);
    t1[4 * q2 + 3] = fmaf(t1[4 * q2 + 3], 0.125f, b1.w);
  }
  float mx = t0[0];
#pragma unroll
  for (int r = 1; r < 16; ++r) mx = fmaxf(mx, t0[r]);
#pragma unroll
  for (int r = 0; r < 16; ++r) mx = fmaxf(mx, t1[r]);
  mx = fmaxf(mx, __shfl_xor(mx, 32));
  float sum = 0.f;
#pragma unroll
  for (int r = 0; r < 16; ++r) { t0[r] = __expf(t0[r] - mx); sum += t0[r]; }
#pragma unroll
  for (int r = 0; r < 16; ++r) { t1[r] = __expf(t1[r] - mx); sum += t1[r]; }
  sum += __shfl_xor(sum, 32);
  return 1.0f / sum;
}

// Pack fp32 weights -> bf16 frag-order: 32 blocks of [64][512] (Wq h0-7, Wk h0-7,
// Wv h0-7, Wo w0-7); cell (td,ke,lane)*8 = W[32*td+l31][16*ke+8*hi+{0..7}].
__global__ __launch_bounds__(256) void prep_weights(
    const float* __restrict__ Wq, const float* __restrict__ Wk,
    const float* __restrict__ Wv, const float* __restrict__ Wo,
    unsigned short* __restrict__ dst) {
  int i = blockIdx.x * 256 + threadIdx.x;   // 131072 cells x 8 elems
  int blk = i >> 12;
  int c = i & 4095;
  int td = c >> 11;
  int ke = (c >> 6) & 31;
  int lane = c & 63;
  int hi = lane >> 5, l31 = lane & 31;
  int row = 32 * td + l31;
  int e = 16 * ke + 8 * hi;
  int seg = blk >> 3, sub = blk & 7;
  const float* base = (seg == 0) ? Wq : (seg == 1) ? Wk : (seg == 2) ? Wv : Wo;
  const float* src = base + (size_t)(sub * 64 + row) * 512 + e;
  float4 v0 = reinterpret_cast<const float4*>(src)[0];
  float4 v1 = reinterpret_cast<const float4*>(src)[1];
  u32x4 o;
  o[0] = pkbf(v0.x, v0.y); o[1] = pkbf(v0.z, v0.w);
  o[2] = pkbf(v1.x, v1.y); o[3] = pkbf(v1.z, v1.w);
  *reinterpret_cast<u32x4*>(dst + (size_t)blk * 32768 + c * 8) = o;
}

// One block per window (2048 blocks), 512 threads = 8 waves, wave w = head w.
// LDS = 64 KiB (XsRs) + 16 KiB (Bm) = 80 KiB -> 2 blocks/CU, 4 waves/EU (128 regs).
// Phases are sequenced so no point holds >~112 live regs (no scratch spill).
__global__ __launch_bounds__(512, 4) void swin_fused(
    const float* __restrict__ patches,
    const float* __restrict__ bq, const float* __restrict__ bk,
    const float* __restrict__ bv, const float* __restrict__ bo,
    const float* __restrict__ posb,
    const unsigned short* __restrict__ Wbf,
    float* __restrict__ out) {
  __shared__ unsigned short XsRs[64 * 512];  // X bf16, swizzled; later aliased by Rs
  __shared__ float Bm[64 * 64];              // bias+mask, granule-swizzled

  const int tid = threadIdx.x;
  const int bid = blockIdx.x;                // ((b*16+y)*16+x)
  const int wxi = bid & 15;
  const int wyi = (bid >> 4) & 15;
  const int w = tid >> 6;
  const int lane = tid & 63;
  const int l31 = lane & 31;
  const int hi = lane >> 5;
  const int h = w;

  // ---- Phase A: stage X (fp32->bf16, 5-bit granule swizzle) + build Bm ----
  const float* Xg = patches + (size_t)bid * 32768;
#pragma unroll
  for (int it = 0; it < 8; ++it) {
    int p = it * 8 + w;
    int e0 = lane << 3;
    const float4* gp = reinterpret_cast<const float4*>(Xg + p * 512 + e0);
    float4 v0 = gp[0], v1 = gp[1];
    u32x4 xv;
    xv[0] = pkbf(v0.x, v0.y); xv[1] = pkbf(v0.z, v0.w);
    xv[2] = pkbf(v1.x, v1.y); xv[3] = pkbf(v1.z, v1.w);
    *reinterpret_cast<u32x4*>(XsRs + p * 512 + (e0 ^ ((p & 31) << 3))) = xv;
  }
#pragma unroll
  for (int ii = 0; ii < 8; ++ii) {
    int i = ii * 512 + tid;
    int p = i >> 6, k = i & 63;
    int pr = p >> 3, pc = p & 7, kr = k >> 3, kc = k & 7;
    float b = posb[(pr - kr + 7) * 15 + (pc - kc + 7)];
    bool mk = ((wyi == 15) && ((pr < 4) != (kr < 4))) ||
              ((wxi == 15) && ((pc < 4) != (kc < 4)));
    Bm[p * 64 + (k ^ ((p & 15) << 2))] = mk ? -1e30f : b;
  }
  __syncthreads();

  // ---- Phase B: K, Q projections; kf+qf die inside Phase C ----
  bf16x8 pf[2][4];   // unnormalized exp(P) frags
  float sinv0, sinv1;
  {
    bf16x8 kf[2][4], qf[2][4];
    projT(Wbf + (size_t)(8 + h) * 32768, bk + h * 64, XsRs, lane, l31, hi, kf);
    projT(Wbf + (size_t)(0 + h) * 32768, bq + h * 64, XsRs, lane, l31, hi, qf);

    // ---- Phase C: S^T = K' Q'^T + softmax, one query-tile tp at a time ----
    const int bswz = (l31 & 15) << 2;
#pragma unroll
    for (int tp = 0; tp < 2; ++tp) {
      f32x16 s0 = z16(), s1 = z16();   // s[tk] for this tp
#pragma unroll
      for (int kd = 0; kd < 4; ++kd) {
        s0 = MFMA32(kf[0][kd], qf[tp][kd], s0);
        s1 = MFMA32(kf[1][kd], qf[tp][kd], s1);
      }
      float si = sm_tp(s0, s1, Bm + (l31 + 32 * tp) * 64, bswz, hi);
      if (tp == 0) sinv0 = si; else sinv1 = si;
      tile2frag(s0, hi, &pf[tp][0], &pf[tp][1]);
      tile2frag(s1, hi, &pf[tp][2], &pf[tp][3]);
    }
  }

  // ---- Phase D: V projection (last Xs reader), vf kept in registers ----
  bf16x8 vf[2][4];   // vf[td][ks] = V^T[d=l31+32td][q-run 16*ks+8*hi+{0..7}]
  {
    const int sw = l31 << 3;
    const unsigned short* xr0 = XsRs + l31 * 512;
    const unsigned short* xr1 = XsRs + (l31 + 32) * 512;
#pragma unroll
    for (int td = 0; td < 2; ++td) {
      f32x16 v0 = z16(), v1 = z16();   // v[tq] for this td
      const unsigned short* wp = Wbf + (size_t)(16 + h) * 32768 + td * 16384 + lane * 8;
#pragma unroll 2
      for (int ke = 0; ke < 32; ++ke) {
        const int eo = 8 * hi + 16 * ke;
        bf16x8 x0 = *reinterpret_cast<const bf16x8*>(xr0 + (eo ^ sw));
        bf16x8 x1 = *reinterpret_cast<const bf16x8*>(xr1 + (eo ^ sw));
        bf16x8 w0 = *reinterpret_cast<const bf16x8*>(wp + ke * 512);
        v0 = MFMA32(x0, w0, v0);
        v1 = MFMA32(x1, w0, v1);
      }
      float bvv = bv[h * 64 + 32 * td + l31];
#pragma unroll
      for (int r = 0; r < 16; ++r) { v0[r] += bvv; v1[r] += bvv; }
      tile2frag(v0, hi, &vf[td][0], &vf[td][1]);
      tile2frag(v1, hi, &vf[td][2], &vf[td][3]);
    }
  }

  __syncthreads();  // all waves done reading Xs; Rs may now overwrite it

  // ---- Phase E: PV per td, normalize, write straight to Rs (no r-tile pileup) ----
#pragma unroll
  for (int td = 0; td < 2; ++td) {
    f32x16 ra = z16(), rb = z16();   // r[td][tp=0], r[td][tp=1]
#pragma unroll
    for (int ks = 0; ks < 4; ++ks) {
      ra = MFMA32(vf[td][ks], pf[0][ks], ra);
      rb = MFMA32(vf[td][ks], pf[1][ks], rb);
    }
#pragma unroll
    for (int r = 0; r < 16; ++r) { ra[r] *= sinv0; rb[r] *= sinv1; }
    // write Rs[p][h*64+d] (aliases Xs, same 5-bit swizzle); tile rows = d
#pragma unroll
    for (int tp = 0; tp < 2; ++tp) {
      int p = l31 + 32 * tp;
      unsigned short* row = XsRs + p * 512;
      int swp = l31 << 3;   // (p & 31) << 3
      const f32x16& t = tp ? rb : ra;
#pragma unroll
      for (int q2 = 0; q2 < 4; ++q2) {
        int ce = h * 64 + 32 * td + 8 * q2 + 4 * hi;
        uint2 val;
        val.x = pkbf(t[4 * q2 + 0], t[4 * q2 + 1]);
        val.y = pkbf(t[4 * q2 + 2], t[4 * q2 + 3]);
        *reinterpret_cast<uint2*>(row + (ce ^ swp)) = val;
      }
    }
  }
  __syncthreads();

  // ---- Phase F: out = Rs @ Wo^T (+bo): wave w owns output cols 64w..64w+63 ----
  f32x16 a00 = z16(), a01 = z16(), a10 = z16(), a11 = z16();  // acc[tp][tc]
  {
    const unsigned short* wp = Wbf + (size_t)(24 + w) * 32768 + lane * 8;
    const int swp = l31 << 3;
#pragma unroll 2
    for (int kc = 0; kc < 32; ++kc) {
      int ko = 8 * hi + 16 * kc;
      bf16x8 ra0 = *reinterpret_cast<const bf16x8*>(XsRs + l31 * 512 + (ko ^ swp));
      bf16x8 ra1 = *reinterpret_cast<const bf16x8*>(XsRs + (l31 + 32) * 512 + (ko ^ swp));
      bf16x8 wo0 = *reinterpret_cast<const bf16x8*>(wp + kc * 512);
      bf16x8 wo1 = *reinterpret_cast<const bf16x8*>(wp + 16384 + kc * 512);
      a00 = MFMA32(ra0, wo0, a00); a01 = MFMA32(ra0, wo1, a01);
      a10 = MFMA32(ra1, wo0, a10); a11 = MFMA32(ra1, wo1, a11);
    }
  }
  float bo0 = bo[64 * w + l31];
  float bo1 = bo[64 * w + l31 + 32];
  float* og = out + (size_t)bid * 32768;
#pragma unroll
  for (int tp = 0; tp < 2; ++tp) {
#pragma unroll
    for (int r = 0; r < 16; ++r) {
      int p = (r & 3) + 8 * (r >> 2) + 4 * hi + 32 * tp;
      const f32x16& t0 = tp ? a10 : a00;
      const f32x16& t1 = tp ? a11 : a01;
      og[p * 512 + 64 * w + l31] = t0[r] + bo0;
      og[p * 512 + 64 * w + l31 + 32] = t1[r] + bo1;
    }
  }
}

extern "C" void kernel_launch(void* const* d_in, const int* in_sizes, int n_in,
                              void* d_out, int out_size, void* d_ws, size_t ws_size,
                              hipStream_t stream) {
  const float* patches = (const float*)d_in[0];
  const float* Wq = (const float*)d_in[1];
  const float* bq = (const float*)d_in[2];
  const float* Wk = (const float*)d_in[3];
  const float* bk = (const float*)d_in[4];
  const float* Wv = (const float*)d_in[5];
  const float* bv = (const float*)d_in[6];
  const float* Wo = (const float*)d_in[7];
  const float* bo = (const float*)d_in[8];
  const float* posb = (const float*)d_in[9];
  // mask (d_in[10]) / bias_idx (d_in[11],[12]) recomputed on device.
  unsigned short* wbf = (unsigned short*)d_ws;   // 2 MiB
  hipLaunchKernelGGL(prep_weights, dim3(512), dim3(256), 0, stream, Wq, Wk, Wv, Wo, wbf);
  hipLaunchKernelGGL(swin_fused, dim3(2048), dim3(512), 0, stream,
                     patches, bq, bk, bv, bo, posb, wbf, (float*)d_out);
}

// Round 7
// 430.332 us; speedup vs baseline: 3.2259x; 1.0033x over previous
//
#include <hip/hip_runtime.h>
#include <hip/hip_bf16.h>

typedef __attribute__((ext_vector_type(8))) short bf16x8;
typedef __attribute__((ext_vector_type(16))) float f32x16;
typedef __attribute__((ext_vector_type(4))) unsigned int u32x4;

#define MFMA32(a, b, c) __builtin_amdgcn_mfma_f32_32x32x16_bf16((a), (b), (c), 0, 0, 0)

static __device__ __forceinline__ unsigned int pkbf(float lo, float hi) {
  unsigned int r;
  asm("v_cvt_pk_bf16_f32 %0, %1, %2" : "=v"(r) : "v"(lo), "v"(hi));
  return r;
}

static __device__ __forceinline__ bf16x8 u4_to_bf8(u32x4 u) {
  union { u32x4 u; bf16x8 b; } cv;
  cv.u = u;
  return cv.b;
}

static __device__ __forceinline__ f32x16 z16() {
  f32x16 z;
#pragma unroll
  for (int i = 0; i < 16; ++i) z[i] = 0.0f;
  return z;
}

// Convert one 32x32 MFMA C-tile (value at [row=(r&3)+8*(r>>2)+4*hi][col=lane&31])
// into two bf16 frags with k-runs taken from the ROW dim: f0 = rows 8*hi+{0..7},
// f1 = rows 16+8*hi+{0..7}, column (lane&31) preserved.
static __device__ __forceinline__ void tile2frag(const f32x16 t, int hi,
                                                 bf16x8* f0, bf16x8* f1) {
  unsigned int a0 = pkbf(t[0], t[1]), a1 = pkbf(t[2], t[3]);
  unsigned int b0 = pkbf(t[4], t[5]), b1 = pkbf(t[6], t[7]);
  unsigned int c0 = pkbf(t[8], t[9]), c1 = pkbf(t[10], t[11]);
  unsigned int d0 = pkbf(t[12], t[13]), d1 = pkbf(t[14], t[15]);
  unsigned int sa0 = __shfl_xor((int)a0, 32), sa1 = __shfl_xor((int)a1, 32);
  unsigned int sb0 = __shfl_xor((int)b0, 32), sb1 = __shfl_xor((int)b1, 32);
  unsigned int sc0 = __shfl_xor((int)c0, 32), sc1 = __shfl_xor((int)c1, 32);
  unsigned int sd0 = __shfl_xor((int)d0, 32), sd1 = __shfl_xor((int)d1, 32);
  u32x4 fa, fb;
  fa[0] = hi ? sb0 : a0; fa[1] = hi ? sb1 : a1;
  fa[2] = hi ? b0 : sa0; fa[3] = hi ? b1 : sa1;
  fb[0] = hi ? sd0 : c0; fb[1] = hi ? sd1 : c1;
  fb[2] = hi ? d0 : sc0; fb[3] = hi ? d1 : sc1;
  *f0 = u4_to_bf8(fa);
  *f1 = u4_to_bf8(fb);
}

// T = (X @ Wg^T + bg)^T via mfma(A=W-frags, B=X rows), SEQUENTIAL over td so only
// 2 C-tiles (32 regs) are live at a time. Wg pre-packed: cell (td,ke,lane)*8.
static __device__ __forceinline__ void projT(
    const unsigned short* __restrict__ Wg, const float* __restrict__ bg,
    const unsigned short* Xs, int lane, int l31, int hi, bf16x8 frag[2][4]) {
  const int sw = l31 << 3;
  const unsigned short* xr0 = Xs + l31 * 512;
  const unsigned short* xr1 = Xs + (l31 + 32) * 512;
#pragma unroll
  for (int td = 0; td < 2; ++td) {
    f32x16 c0 = z16(), c1 = z16();   // c[tq] for this td
    const unsigned short* wp = Wg + td * 16384 + lane * 8;
#pragma unroll 2
    for (int ke = 0; ke < 32; ++ke) {
      const int eo = 8 * hi + 16 * ke;
      bf16x8 x0 = *reinterpret_cast<const bf16x8*>(xr0 + (eo ^ sw));
      bf16x8 x1 = *reinterpret_cast<const bf16x8*>(xr1 + (eo ^ sw));
      bf16x8 w0 = *reinterpret_cast<const bf16x8*>(wp + ke * 512);
      c0 = MFMA32(w0, x0, c0);
      c1 = MFMA32(w0, x1, c1);
    }
    const float* bb = bg + 32 * td;
#pragma unroll
    for (int q2 = 0; q2 < 4; ++q2) {
      float4 b0 = *reinterpret_cast<const float4*>(bb + 8 * q2 + 4 * hi);
      c0[4 * q2 + 0] += b0.x; c0[4 * q2 + 1] += b0.y;
      c0[4 * q2 + 2] += b0.z; c0[4 * q2 + 3] += b0.w;
      c1[4 * q2 + 0] += b0.x; c1[4 * q2 + 1] += b0.y;
      c1[4 * q2 + 2] += b0.z; c1[4 * q2 + 3] += b0.w;
    }
    tile2frag(c0, hi, &frag[0][2 * td], &frag[0][2 * td + 1]);
    tile2frag(c1, hi, &frag[1][2 * td], &frag[1][2 * td + 1]);
  }
}

// Scale + bias/mask + softmax for one query tile. A lane holds only HALF the keys
// (hi-interleaved rows); lane l^32 holds the complement -> combine via shfl_xor(32).
static __device__ __forceinline__ float sm_tp(f32x16& t0, f32x16& t1,
                                              const float* BmRow, int swz, int hi) {
#pragma unroll
  for (int q2 = 0; q2 < 4; ++q2) {
    float4 b0 = *reinterpret_cast<const float4*>(BmRow + ((8 * q2 + 4 * hi) ^ swz));
    float4 b1 = *reinterpret_cast<const float4*>(BmRow + ((32 + 8 * q2 + 4 * hi) ^ swz));
    t0[4 * q2 + 0] = fmaf(t0[4 * q2 + 0], 0.125f, b0.x);
    t0[4 * q2 + 1] = fmaf(t0[4 * q2 + 1], 0.125f, b0.y);
    t0[4 * q2 + 2] = fmaf(t0[4 * q2 + 2], 0.125f, b0.z);
    t0[4 * q2 + 3] = fmaf(t0[4 * q2 + 3], 0.125f, b0.w);
    t1[4 * q2 + 0] = fmaf(t1[4 * q2 + 0], 0.125f, b1.x);
    t1[4 * q2 + 1] = fmaf(t1[4 * q2 + 1], 0.125f, b1.y);
    t1[4 * q2 + 2] = fmaf(t1[4 * q2 + 2], 0.125f, b1.z);
    t1[4 * q2 + 3] = fmaf(t1[4 * q2 + 3], 0.125f, b1.w);
  }
  float mx = t0[0];
#pragma unroll
  for (int r = 1; r < 16; ++r) mx = fmaxf(mx, t0[r]);
#pragma unroll
  for (int r = 0; r < 16; ++r) mx = fmaxf(mx, t1[r]);
  mx = fmaxf(mx, __shfl_xor(mx, 32));
  float sum = 0.f;
#pragma unroll
  for (int r = 0; r < 16; ++r) { t0[r] = __expf(t0[r] - mx); sum += t0[r]; }
#pragma unroll
  for (int r = 0; r < 16; ++r) { t1[r] = __expf(t1[r] - mx); sum += t1[r]; }
  sum += __shfl_xor(sum, 32);
  return 1.0f / sum;
}

// Pack fp32 weights -> bf16 frag-order: 32 blocks of [64][512] (Wq h0-7, Wk h0-7,
// Wv h0-7, Wo w0-7); cell (td,ke,lane)*8 = W[32*td+l31][16*ke+8*hi+{0..7}].
__global__ __launch_bounds__(256) void prep_weights(
    const float* __restrict__ Wq, const float* __restrict__ Wk,
    const float* __restrict__ Wv, const float* __restrict__ Wo,
    unsigned short* __restrict__ dst) {
  int i = blockIdx.x * 256 + threadIdx.x;   // 131072 cells x 8 elems
  int blk = i >> 12;
  int c = i & 4095;
  int td = c >> 11;
  int ke = (c >> 6) & 31;
  int lane = c & 63;
  int hi = lane >> 5, l31 = lane & 31;
  int row = 32 * td + l31;
  int e = 16 * ke + 8 * hi;
  int seg = blk >> 3, sub = blk & 7;
  const float* base = (seg == 0) ? Wq : (seg == 1) ? Wk : (seg == 2) ? Wv : Wo;
  const float* src = base + (size_t)(sub * 64 + row) * 512 + e;
  float4 v0 = reinterpret_cast<const float4*>(src)[0];
  float4 v1 = reinterpret_cast<const float4*>(src)[1];
  u32x4 o;
  o[0] = pkbf(v0.x, v0.y); o[1] = pkbf(v0.z, v0.w);
  o[2] = pkbf(v1.x, v1.y); o[3] = pkbf(v1.z, v1.w);
  *reinterpret_cast<u32x4*>(dst + (size_t)blk * 32768 + c * 8) = o;
}

// One block per window (2048 blocks), 512 threads = 8 waves, wave w = head w.
// LDS = 64 KiB (XsRs) + 16 KiB (Bm) = 80 KiB -> 2 blocks/CU, 4 waves/EU (128 regs).
// Max simultaneous MFMA accumulator tiles anywhere = 2 (32 AGPR) so the unified
// file can split ~96 VGPR / 32 AGPR instead of 64/64 (which spilled).
__global__ __launch_bounds__(512, 4) void swin_fused(
    const float* __restrict__ patches,
    const float* __restrict__ bq, const float* __restrict__ bk,
    const float* __restrict__ bv, const float* __restrict__ bo,
    const float* __restrict__ posb,
    const unsigned short* __restrict__ Wbf,
    float* __restrict__ out) {
  __shared__ unsigned short XsRs[64 * 512];  // X bf16, swizzled; later aliased by Rs
  __shared__ float Bm[64 * 64];              // bias+mask, granule-swizzled

  const int tid = threadIdx.x;
  const int bid = blockIdx.x;                // ((b*16+y)*16+x)
  const int wxi = bid & 15;
  const int wyi = (bid >> 4) & 15;
  const int w = tid >> 6;
  const int lane = tid & 63;
  const int l31 = lane & 31;
  const int hi = lane >> 5;
  const int h = w;

  // ---- Phase A: stage X (fp32->bf16, 5-bit granule swizzle) + build Bm ----
  const float* Xg = patches + (size_t)bid * 32768;
#pragma unroll
  for (int it = 0; it < 8; ++it) {
    int p = it * 8 + w;
    int e0 = lane << 3;
    const float4* gp = reinterpret_cast<const float4*>(Xg + p * 512 + e0);
    float4 v0 = gp[0], v1 = gp[1];
    u32x4 xv;
    xv[0] = pkbf(v0.x, v0.y); xv[1] = pkbf(v0.z, v0.w);
    xv[2] = pkbf(v1.x, v1.y); xv[3] = pkbf(v1.z, v1.w);
    *reinterpret_cast<u32x4*>(XsRs + p * 512 + (e0 ^ ((p & 31) << 3))) = xv;
  }
#pragma unroll
  for (int ii = 0; ii < 8; ++ii) {
    int i = ii * 512 + tid;
    int p = i >> 6, k = i & 63;
    int pr = p >> 3, pc = p & 7, kr = k >> 3, kc = k & 7;
    float b = posb[(pr - kr + 7) * 15 + (pc - kc + 7)];
    bool mk = ((wyi == 15) && ((pr < 4) != (kr < 4))) ||
              ((wxi == 15) && ((pc < 4) != (kc < 4)));
    Bm[p * 64 + (k ^ ((p & 15) << 2))] = mk ? -1e30f : b;
  }
  __syncthreads();

  // ---- Phase B: K, Q projections; kf+qf die inside Phase C ----
  bf16x8 pf[2][4];   // unnormalized exp(P) frags
  float sinv0, sinv1;
  {
    bf16x8 kf[2][4], qf[2][4];
    projT(Wbf + (size_t)(8 + h) * 32768, bk + h * 64, XsRs, lane, l31, hi, kf);
    projT(Wbf + (size_t)(0 + h) * 32768, bq + h * 64, XsRs, lane, l31, hi, qf);

    // ---- Phase C: S^T = K' Q'^T + softmax, one query-tile tp at a time ----
    const int bswz = (l31 & 15) << 2;
#pragma unroll
    for (int tp = 0; tp < 2; ++tp) {
      f32x16 s0 = z16(), s1 = z16();   // s[tk] for this tp
#pragma unroll
      for (int kd = 0; kd < 4; ++kd) {
        s0 = MFMA32(kf[0][kd], qf[tp][kd], s0);
        s1 = MFMA32(kf[1][kd], qf[tp][kd], s1);
      }
      float si = sm_tp(s0, s1, Bm + (l31 + 32 * tp) * 64, bswz, hi);
      if (tp == 0) sinv0 = si; else sinv1 = si;
      tile2frag(s0, hi, &pf[tp][0], &pf[tp][1]);
      tile2frag(s1, hi, &pf[tp][2], &pf[tp][3]);
    }
  }

  // ---- Phase D: V projection (last Xs reader), vf kept in registers ----
  bf16x8 vf[2][4];   // vf[td][ks] = V^T[d=l31+32td][q-run 16*ks+8*hi+{0..7}]
  {
    const int sw = l31 << 3;
    const unsigned short* xr0 = XsRs + l31 * 512;
    const unsigned short* xr1 = XsRs + (l31 + 32) * 512;
#pragma unroll
    for (int td = 0; td < 2; ++td) {
      f32x16 v0 = z16(), v1 = z16();   // v[tq] for this td
      const unsigned short* wp = Wbf + (size_t)(16 + h) * 32768 + td * 16384 + lane * 8;
#pragma unroll 2
      for (int ke = 0; ke < 32; ++ke) {
        const int eo = 8 * hi + 16 * ke;
        bf16x8 x0 = *reinterpret_cast<const bf16x8*>(xr0 + (eo ^ sw));
        bf16x8 x1 = *reinterpret_cast<const bf16x8*>(xr1 + (eo ^ sw));
        bf16x8 w0 = *reinterpret_cast<const bf16x8*>(wp + ke * 512);
        v0 = MFMA32(x0, w0, v0);
        v1 = MFMA32(x1, w0, v1);
      }
      float bvv = bv[h * 64 + 32 * td + l31];
#pragma unroll
      for (int r = 0; r < 16; ++r) { v0[r] += bvv; v1[r] += bvv; }
      tile2frag(v0, hi, &vf[td][0], &vf[td][1]);
      tile2frag(v1, hi, &vf[td][2], &vf[td][3]);
    }
  }

  __syncthreads();  // all waves done reading Xs; Rs may now overwrite it

  // ---- Phase E: PV per td, normalize, write straight to Rs ----
#pragma unroll
  for (int td = 0; td < 2; ++td) {
    f32x16 ra = z16(), rb = z16();   // r[td][tp=0], r[td][tp=1]
#pragma unroll
    for (int ks = 0; ks < 4; ++ks) {
      ra = MFMA32(vf[td][ks], pf[0][ks], ra);
      rb = MFMA32(vf[td][ks], pf[1][ks], rb);
    }
#pragma unroll
    for (int r = 0; r < 16; ++r) { ra[r] *= sinv0; rb[r] *= sinv1; }
    // write Rs[p][h*64+d] (aliases Xs, same 5-bit swizzle); tile rows = d
#pragma unroll
    for (int tp = 0; tp < 2; ++tp) {
      int p = l31 + 32 * tp;
      unsigned short* row = XsRs + p * 512;
      int swp = l31 << 3;   // (p & 31) << 3
      const f32x16& t = tp ? rb : ra;
#pragma unroll
      for (int q2 = 0; q2 < 4; ++q2) {
        int ce = h * 64 + 32 * td + 8 * q2 + 4 * hi;
        uint2 val;
        val.x = pkbf(t[4 * q2 + 0], t[4 * q2 + 1]);
        val.y = pkbf(t[4 * q2 + 2], t[4 * q2 + 3]);
        *reinterpret_cast<uint2*>(row + (ce ^ swp)) = val;
      }
    }
  }
  __syncthreads();

  // ---- Phase F: out = Rs @ Wo^T (+bo), one output-col tile tc at a time ----
  // (2 acc tiles = 32 AGPR max; each tc half reads its own Wo stream once,
  //  Rs re-read from LDS is free)
  float* og = out + (size_t)bid * 32768;
  const int swp = l31 << 3;
#pragma unroll
  for (int tc = 0; tc < 2; ++tc) {
    f32x16 a0 = z16(), a1 = z16();   // acc[tp=0], acc[tp=1] for this tc
    const unsigned short* wp = Wbf + (size_t)(24 + w) * 32768 + tc * 16384 + lane * 8;
#pragma unroll 2
    for (int kc = 0; kc < 32; ++kc) {
      int ko = 8 * hi + 16 * kc;
      bf16x8 ra0 = *reinterpret_cast<const bf16x8*>(XsRs + l31 * 512 + (ko ^ swp));
      bf16x8 ra1 = *reinterpret_cast<const bf16x8*>(XsRs + (l31 + 32) * 512 + (ko ^ swp));
      bf16x8 wo = *reinterpret_cast<const bf16x8*>(wp + kc * 512);
      a0 = MFMA32(ra0, wo, a0);
      a1 = MFMA32(ra1, wo, a1);
    }
    float bov = bo[64 * w + 32 * tc + l31];
#pragma unroll
    for (int tp = 0; tp < 2; ++tp) {
      const f32x16& t = tp ? a1 : a0;
#pragma unroll
      for (int r = 0; r < 16; ++r) {
        int p = (r & 3) + 8 * (r >> 2) + 4 * hi + 32 * tp;
        og[p * 512 + 64 * w + 32 * tc + l31] = t[r] + bov;
      }
    }
  }
}

extern "C" void kernel_launch(void* const* d_in, const int* in_sizes, int n_in,
                              void* d_out, int out_size, void* d_ws, size_t ws_size,
                              hipStream_t stream) {
  const float* patches = (const float*)d_in[0];
  const float* Wq = (const float*)d_in[1];
  const float* bq = (const float*)d_in[2];
  const float* Wk = (const float*)d_in[3];
  const float* bk = (const float*)d_in[4];
  const float* Wv = (const float*)d_in[5];
  const float* bv = (const float*)d_in[6];
  const float* Wo = (const float*)d_in[7];
  const float* bo = (const float*)d_in[8];
  const float* posb = (const float*)d_in[9];
  // mask (d_in[10]) / bias_idx (d_in[11],[12]) recomputed on device.
  unsigned short* wbf = (unsigned short*)d_ws;   // 2 MiB
  hipLaunchKernelGGL(prep_weights, dim3(512), dim3(256), 0, stream, Wq, Wk, Wv, Wo, wbf);
  hipLaunchKernelGGL(swin_fused, dim3(2048), dim3(512), 0, stream,
                     patches, bq, bk, bv, bo, posb, wbf, (float*)d_out);
}

// Round 8
// 394.281 us; speedup vs baseline: 3.5209x; 1.0914x over previous
//
#include <hip/hip_runtime.h>
#include <hip/hip_bf16.h>

typedef __attribute__((ext_vector_type(8))) short bf16x8;
typedef __attribute__((ext_vector_type(16))) float f32x16;
typedef __attribute__((ext_vector_type(4))) unsigned int u32x4;

#define MFMA32(a, b, c) __builtin_amdgcn_mfma_f32_32x32x16_bf16((a), (b), (c), 0, 0, 0)

static __device__ __forceinline__ unsigned int pkbf(float lo, float hi) {
  unsigned int r;
  asm("v_cvt_pk_bf16_f32 %0, %1, %2" : "=v"(r) : "v"(lo), "v"(hi));
  return r;
}

static __device__ __forceinline__ bf16x8 u4_to_bf8(u32x4 u) {
  union { u32x4 u; bf16x8 b; } cv;
  cv.u = u;
  return cv.b;
}

static __device__ __forceinline__ f32x16 z16() {
  f32x16 z;
#pragma unroll
  for (int i = 0; i < 16; ++i) z[i] = 0.0f;
  return z;
}

// Convert one 32x32 MFMA C-tile (value at [row=(r&3)+8*(r>>2)+4*hi][col=lane&31])
// into two bf16 frags with k-runs taken from the ROW dim: f0 = rows 8*hi+{0..7},
// f1 = rows 16+8*hi+{0..7}, column (lane&31) preserved.
static __device__ __forceinline__ void tile2frag(const f32x16 t, int hi,
                                                 bf16x8* f0, bf16x8* f1) {
  unsigned int a0 = pkbf(t[0], t[1]), a1 = pkbf(t[2], t[3]);
  unsigned int b0 = pkbf(t[4], t[5]), b1 = pkbf(t[6], t[7]);
  unsigned int c0 = pkbf(t[8], t[9]), c1 = pkbf(t[10], t[11]);
  unsigned int d0 = pkbf(t[12], t[13]), d1 = pkbf(t[14], t[15]);
  unsigned int sa0 = __shfl_xor((int)a0, 32), sa1 = __shfl_xor((int)a1, 32);
  unsigned int sb0 = __shfl_xor((int)b0, 32), sb1 = __shfl_xor((int)b1, 32);
  unsigned int sc0 = __shfl_xor((int)c0, 32), sc1 = __shfl_xor((int)c1, 32);
  unsigned int sd0 = __shfl_xor((int)d0, 32), sd1 = __shfl_xor((int)d1, 32);
  u32x4 fa, fb;
  fa[0] = hi ? sb0 : a0; fa[1] = hi ? sb1 : a1;
  fa[2] = hi ? b0 : sa0; fa[3] = hi ? b1 : sa1;
  fb[0] = hi ? sd0 : c0; fb[1] = hi ? sd1 : c1;
  fb[2] = hi ? d0 : sc0; fb[3] = hi ? d1 : sc1;
  *f0 = u4_to_bf8(fa);
  *f1 = u4_to_bf8(fb);
}

// T = (X @ Wg^T + bg)^T via mfma(A=W-frags, B=X rows), 4 parallel C-tiles
// (registers allow it at 256 regs/wave). Wg pre-packed: cell (td,ke,lane)*8.
static __device__ __forceinline__ void projT4(
    const unsigned short* __restrict__ Wg, const float* __restrict__ bg,
    const unsigned short* Xs, int lane, int l31, int hi, bf16x8 frag[2][4]) {
  f32x16 c00 = z16(), c01 = z16(), c10 = z16(), c11 = z16();  // c[td][tq]
  const int sw = l31 << 3;
  const unsigned short* xr0 = Xs + l31 * 512;
  const unsigned short* xr1 = Xs + (l31 + 32) * 512;
  const unsigned short* wp = Wg + lane * 8;
#pragma unroll 2
  for (int ke = 0; ke < 32; ++ke) {
    const int eo = 8 * hi + 16 * ke;
    bf16x8 x0 = *reinterpret_cast<const bf16x8*>(xr0 + (eo ^ sw));
    bf16x8 x1 = *reinterpret_cast<const bf16x8*>(xr1 + (eo ^ sw));
    bf16x8 w0 = *reinterpret_cast<const bf16x8*>(wp + ke * 512);
    bf16x8 w1 = *reinterpret_cast<const bf16x8*>(wp + 16384 + ke * 512);
    c00 = MFMA32(w0, x0, c00); c01 = MFMA32(w0, x1, c01);
    c10 = MFMA32(w1, x0, c10); c11 = MFMA32(w1, x1, c11);
  }
#pragma unroll
  for (int q2 = 0; q2 < 4; ++q2) {
    float4 b0 = *reinterpret_cast<const float4*>(bg + 8 * q2 + 4 * hi);
    float4 b1 = *reinterpret_cast<const float4*>(bg + 32 + 8 * q2 + 4 * hi);
    c00[4 * q2 + 0] += b0.x; c00[4 * q2 + 1] += b0.y;
    c00[4 * q2 + 2] += b0.z; c00[4 * q2 + 3] += b0.w;
    c01[4 * q2 + 0] += b0.x; c01[4 * q2 + 1] += b0.y;
    c01[4 * q2 + 2] += b0.z; c01[4 * q2 + 3] += b0.w;
    c10[4 * q2 + 0] += b1.x; c10[4 * q2 + 1] += b1.y;
    c10[4 * q2 + 2] += b1.z; c10[4 * q2 + 3] += b1.w;
    c11[4 * q2 + 0] += b1.x; c11[4 * q2 + 1] += b1.y;
    c11[4 * q2 + 2] += b1.z; c11[4 * q2 + 3] += b1.w;
  }
  tile2frag(c00, hi, &frag[0][0], &frag[0][1]);
  tile2frag(c10, hi, &frag[0][2], &frag[0][3]);
  tile2frag(c01, hi, &frag[1][0], &frag[1][1]);
  tile2frag(c11, hi, &frag[1][2], &frag[1][3]);
}

// Scale + bias/mask + softmax for one query tile. A lane holds only HALF the keys
// (hi-interleaved rows); lane l^32 holds the complement -> combine via shfl_xor(32).
static __device__ __forceinline__ float sm_tp(f32x16& t0, f32x16& t1,
                                              const float* BmRow, int swz, int hi) {
#pragma unroll
  for (int q2 = 0; q2 < 4; ++q2) {
    float4 b0 = *reinterpret_cast<const float4*>(BmRow + ((8 * q2 + 4 * hi) ^ swz));
    float4 b1 = *reinterpret_cast<const float4*>(BmRow + ((32 + 8 * q2 + 4 * hi) ^ swz));
    t0[4 * q2 + 0] = fmaf(t0[4 * q2 + 0], 0.125f, b0.x);
    t0[4 * q2 + 1] = fmaf(t0[4 * q2 + 1], 0.125f, b0.y);
    t0[4 * q2 + 2] = fmaf(t0[4 * q2 + 2], 0.125f, b0.z);
    t0[4 * q2 + 3] = fmaf(t0[4 * q2 + 3], 0.125f, b0.w);
    t1[4 * q2 + 0] = fmaf(t1[4 * q2 + 0], 0.125f, b1.x);
    t1[4 * q2 + 1] = fmaf(t1[4 * q2 + 1], 0.125f, b1.y);
    t1[4 * q2 + 2] = fmaf(t1[4 * q2 + 2], 0.125f, b1.z);
    t1[4 * q2 + 3] = fmaf(t1[4 * q2 + 3], 0.125f, b1.w);
  }
  float mx = t0[0];
#pragma unroll
  for (int r = 1; r < 16; ++r) mx = fmaxf(mx, t0[r]);
#pragma unroll
  for (int r = 0; r < 16; ++r) mx = fmaxf(mx, t1[r]);
  mx = fmaxf(mx, __shfl_xor(mx, 32));
  float sum = 0.f;
#pragma unroll
  for (int r = 0; r < 16; ++r) { t0[r] = __expf(t0[r] - mx); sum += t0[r]; }
#pragma unroll
  for (int r = 0; r < 16; ++r) { t1[r] = __expf(t1[r] - mx); sum += t1[r]; }
  sum += __shfl_xor(sum, 32);
  return 1.0f / sum;
}

// Pack fp32 weights -> bf16 frag-order: 32 blocks of [64][512] (Wq h0-7, Wk h0-7,
// Wv h0-7, Wo w0-7); cell (td,ke,lane)*8 = W[32*td+l31][16*ke+8*hi+{0..7}].
__global__ __launch_bounds__(256) void prep_weights(
    const float* __restrict__ Wq, const float* __restrict__ Wk,
    const float* __restrict__ Wv, const float* __restrict__ Wo,
    unsigned short* __restrict__ dst) {
  int i = blockIdx.x * 256 + threadIdx.x;   // 131072 cells x 8 elems
  int blk = i >> 12;
  int c = i & 4095;
  int td = c >> 11;
  int ke = (c >> 6) & 31;
  int lane = c & 63;
  int hi = lane >> 5, l31 = lane & 31;
  int row = 32 * td + l31;
  int e = 16 * ke + 8 * hi;
  int seg = blk >> 3, sub = blk & 7;
  const float* base = (seg == 0) ? Wq : (seg == 1) ? Wk : (seg == 2) ? Wv : Wo;
  const float* src = base + (size_t)(sub * 64 + row) * 512 + e;
  float4 v0 = reinterpret_cast<const float4*>(src)[0];
  float4 v1 = reinterpret_cast<const float4*>(src)[1];
  u32x4 o;
  o[0] = pkbf(v0.x, v0.y); o[1] = pkbf(v0.z, v0.w);
  o[2] = pkbf(v1.x, v1.y); o[3] = pkbf(v1.z, v1.w);
  *reinterpret_cast<u32x4*>(dst + (size_t)blk * 32768 + c * 8) = o;
}

// One block per window (2048 blocks), 256 threads = 4 waves; wave w handles
// heads {w, w+4} sequentially. LDS = 64 KiB (XsRs) + 16 KiB (Bm) = 80 KiB ->
// 2 blocks/CU (independent: barrier overlap), 2 waves/SIMD -> 256 regs/wave:
// the full per-head live set (~190 regs) fits with ZERO scratch spill.
__global__ __launch_bounds__(256, 2) void swin_fused(
    const float* __restrict__ patches,
    const float* __restrict__ bq, const float* __restrict__ bk,
    const float* __restrict__ bv, const float* __restrict__ bo,
    const float* __restrict__ posb,
    const unsigned short* __restrict__ Wbf,
    float* __restrict__ out) {
  __shared__ unsigned short XsRs[64 * 512];  // X bf16, swizzled; later aliased by Rs
  __shared__ float Bm[64 * 64];              // bias+mask, granule-swizzled

  const int tid = threadIdx.x;
  const int bid = blockIdx.x;                // ((b*16+y)*16+x)
  const int wxi = bid & 15;
  const int wyi = (bid >> 4) & 15;
  const int w = tid >> 6;                    // wave 0..3
  const int lane = tid & 63;
  const int l31 = lane & 31;
  const int hi = lane >> 5;

  // ---- Phase A: stage X (fp32->bf16, 5-bit granule swizzle) + build Bm ----
  const float* Xg = patches + (size_t)bid * 32768;
#pragma unroll
  for (int it = 0; it < 16; ++it) {
    int p = it * 4 + w;
    int e0 = lane << 3;
    const float4* gp = reinterpret_cast<const float4*>(Xg + p * 512 + e0);
    float4 v0 = gp[0], v1 = gp[1];
    u32x4 xv;
    xv[0] = pkbf(v0.x, v0.y); xv[1] = pkbf(v0.z, v0.w);
    xv[2] = pkbf(v1.x, v1.y); xv[3] = pkbf(v1.z, v1.w);
    *reinterpret_cast<u32x4*>(XsRs + p * 512 + (e0 ^ ((p & 31) << 3))) = xv;
  }
#pragma unroll
  for (int ii = 0; ii < 16; ++ii) {
    int i = ii * 256 + tid;
    int p = i >> 6, k = i & 63;
    int pr = p >> 3, pc = p & 7, kr = k >> 3, kc = k & 7;
    float b = posb[(pr - kr + 7) * 15 + (pc - kc + 7)];
    bool mk = ((wyi == 15) && ((pr < 4) != (kr < 4))) ||
              ((wxi == 15) && ((pc < 4) != (kc < 4)));
    Bm[p * 64 + (k ^ ((p & 15) << 2))] = mk ? -1e30f : b;
  }
  __syncthreads();

  // ---- Per-head pipeline, 2 heads per wave; R packed in regs until Xs dead ----
  uint2 rst[2][2][2][4];   // [hh][tp][td][q2] - static indexing only
  const int bswz = (l31 & 15) << 2;
#pragma unroll
  for (int hh = 0; hh < 2; ++hh) {
    const int h = w + 4 * hh;
    // Phase B: K, Q projections
    bf16x8 kf[2][4], qf[2][4];
    projT4(Wbf + (size_t)(8 + h) * 32768, bk + h * 64, XsRs, lane, l31, hi, kf);
    projT4(Wbf + (size_t)(0 + h) * 32768, bq + h * 64, XsRs, lane, l31, hi, qf);

    // Phase C: S^T = K' Q'^T (4 parallel tiles) + softmax
    f32x16 s00 = z16(), s01 = z16(), s10 = z16(), s11 = z16();  // s[tk][tp]
#pragma unroll
    for (int kd = 0; kd < 4; ++kd) {
      s00 = MFMA32(kf[0][kd], qf[0][kd], s00);
      s01 = MFMA32(kf[0][kd], qf[1][kd], s01);
      s10 = MFMA32(kf[1][kd], qf[0][kd], s10);
      s11 = MFMA32(kf[1][kd], qf[1][kd], s11);
    }
    float sinv0 = sm_tp(s00, s10, Bm + l31 * 64, bswz, hi);
    float sinv1 = sm_tp(s01, s11, Bm + (l31 + 32) * 64, bswz, hi);
    bf16x8 pf[2][4];
    tile2frag(s00, hi, &pf[0][0], &pf[0][1]);
    tile2frag(s10, hi, &pf[0][2], &pf[0][3]);
    tile2frag(s01, hi, &pf[1][0], &pf[1][1]);
    tile2frag(s11, hi, &pf[1][2], &pf[1][3]);

    // Phase D: V projection (4 parallel tiles), frags straight from C-tiles
    bf16x8 vf[2][4];   // vf[td][ks]
    {
      f32x16 v00 = z16(), v01 = z16(), v10 = z16(), v11 = z16();  // v[tq][td]
      const int sw = l31 << 3;
      const unsigned short* xr0 = XsRs + l31 * 512;
      const unsigned short* xr1 = XsRs + (l31 + 32) * 512;
      const unsigned short* wp = Wbf + (size_t)(16 + h) * 32768 + lane * 8;
#pragma unroll 2
      for (int ke = 0; ke < 32; ++ke) {
        const int eo = 8 * hi + 16 * ke;
        bf16x8 x0 = *reinterpret_cast<const bf16x8*>(xr0 + (eo ^ sw));
        bf16x8 x1 = *reinterpret_cast<const bf16x8*>(xr1 + (eo ^ sw));
        bf16x8 w0 = *reinterpret_cast<const bf16x8*>(wp + ke * 512);
        bf16x8 w1 = *reinterpret_cast<const bf16x8*>(wp + 16384 + ke * 512);
        v00 = MFMA32(x0, w0, v00); v01 = MFMA32(x0, w1, v01);
        v10 = MFMA32(x1, w0, v10); v11 = MFMA32(x1, w1, v11);
      }
      float bv0 = bv[h * 64 + l31];
      float bv1 = bv[h * 64 + l31 + 32];
#pragma unroll
      for (int r = 0; r < 16; ++r) {
        v00[r] += bv0; v10[r] += bv0;
        v01[r] += bv1; v11[r] += bv1;
      }
      tile2frag(v00, hi, &vf[0][0], &vf[0][1]);
      tile2frag(v10, hi, &vf[0][2], &vf[0][3]);
      tile2frag(v01, hi, &vf[1][0], &vf[1][1]);
      tile2frag(v11, hi, &vf[1][2], &vf[1][3]);
    }

    // Phase E: R^T = V^T @ P (4 parallel tiles), normalize, pack to regs
    f32x16 r00 = z16(), r01 = z16(), r10 = z16(), r11 = z16();  // r[td][tp]
#pragma unroll
    for (int ks = 0; ks < 4; ++ks) {
      r00 = MFMA32(vf[0][ks], pf[0][ks], r00); r01 = MFMA32(vf[0][ks], pf[1][ks], r01);
      r10 = MFMA32(vf[1][ks], pf[0][ks], r10); r11 = MFMA32(vf[1][ks], pf[1][ks], r11);
    }
#pragma unroll
    for (int r = 0; r < 16; ++r) {
      r00[r] *= sinv0; r10[r] *= sinv0;
      r01[r] *= sinv1; r11[r] *= sinv1;
    }
#pragma unroll
    for (int tp = 0; tp < 2; ++tp) {
      const f32x16& t0 = tp ? r01 : r00;   // td = 0
      const f32x16& t1 = tp ? r11 : r10;   // td = 1
#pragma unroll
      for (int q2 = 0; q2 < 4; ++q2) {
        rst[hh][tp][0][q2].x = pkbf(t0[4 * q2 + 0], t0[4 * q2 + 1]);
        rst[hh][tp][0][q2].y = pkbf(t0[4 * q2 + 2], t0[4 * q2 + 3]);
        rst[hh][tp][1][q2].x = pkbf(t1[4 * q2 + 0], t1[4 * q2 + 1]);
        rst[hh][tp][1][q2].y = pkbf(t1[4 * q2 + 2], t1[4 * q2 + 3]);
      }
    }
  }

  __syncthreads();  // all waves done reading Xs; Rs may now overwrite it

  // ---- write both heads' R to Rs[p][h*64+d] (aliases Xs, same swizzle) ----
#pragma unroll
  for (int hh = 0; hh < 2; ++hh) {
    const int h = w + 4 * hh;
#pragma unroll
    for (int tp = 0; tp < 2; ++tp) {
      int p = l31 + 32 * tp;
      unsigned short* row = XsRs + p * 512;
      int swp = l31 << 3;   // (p & 31) << 3
#pragma unroll
      for (int td = 0; td < 2; ++td) {
#pragma unroll
        for (int q2 = 0; q2 < 4; ++q2) {
          int ce = h * 64 + 32 * td + 8 * q2 + 4 * hi;
          *reinterpret_cast<uint2*>(row + (ce ^ swp)) = rst[hh][tp][td][q2];
        }
      }
    }
  }
  __syncthreads();

  // ---- Phase F: out = Rs @ Wo^T (+bo); wave w owns cols 128w..128w+127 ----
  float* og = out + (size_t)bid * 32768;
  const int swp = l31 << 3;
#pragma unroll
  for (int pass = 0; pass < 2; ++pass) {
    // packed Wo block (24 + 2w + pass) covers cols 128w+64*pass..+64; j = td half
    f32x16 a00 = z16(), a01 = z16(), a10 = z16(), a11 = z16();  // a[j][tp]
    const unsigned short* wp0 =
        Wbf + (size_t)(24 + 2 * w + pass) * 32768 + lane * 8;
    const unsigned short* wp1 = wp0 + 16384;
#pragma unroll 2
    for (int kc = 0; kc < 32; ++kc) {
      int ko = 8 * hi + 16 * kc;
      bf16x8 ra0 = *reinterpret_cast<const bf16x8*>(XsRs + l31 * 512 + (ko ^ swp));
      bf16x8 ra1 = *reinterpret_cast<const bf16x8*>(XsRs + (l31 + 32) * 512 + (ko ^ swp));
      bf16x8 wo0 = *reinterpret_cast<const bf16x8*>(wp0 + kc * 512);
      bf16x8 wo1 = *reinterpret_cast<const bf16x8*>(wp1 + kc * 512);
      a00 = MFMA32(ra0, wo0, a00); a01 = MFMA32(ra1, wo0, a01);
      a10 = MFMA32(ra0, wo1, a10); a11 = MFMA32(ra1, wo1, a11);
    }
#pragma unroll
    for (int j = 0; j < 2; ++j) {
      int col0 = 128 * w + 64 * pass + 32 * j + l31;
      float bov = bo[col0];
#pragma unroll
      for (int tp = 0; tp < 2; ++tp) {
        const f32x16& t = j ? (tp ? a11 : a10) : (tp ? a01 : a00);
#pragma unroll
        for (int r = 0; r < 16; ++r) {
          int p = (r & 3) + 8 * (r >> 2) + 4 * hi + 32 * tp;
          og[p * 512 + col0] = t[r] + bov;
        }
      }
    }
  }
}

extern "C" void kernel_launch(void* const* d_in, const int* in_sizes, int n_in,
                              void* d_out, int out_size, void* d_ws, size_t ws_size,
                              hipStream_t stream) {
  const float* patches = (const float*)d_in[0];
  const float* Wq = (const float*)d_in[1];
  const float* bq = (const float*)d_in[2];
  const float* Wk = (const float*)d_in[3];
  const float* bk = (const float*)d_in[4];
  const float* Wv = (const float*)d_in[5];
  const float* bv = (const float*)d_in[6];
  const float* Wo = (const float*)d_in[7];
  const float* bo = (const float*)d_in[8];
  const float* posb = (const float*)d_in[9];
  // mask (d_in[10]) / bias_idx (d_in[11],[12]) recomputed on device.
  unsigned short* wbf = (unsigned short*)d_ws;   // 2 MiB
  hipLaunchKernelGGL(prep_weights, dim3(512), dim3(256), 0, stream, Wq, Wk, Wv, Wo, wbf);
  hipLaunchKernelGGL(swin_fused, dim3(2048), dim3(256), 0, stream,
                     patches, bq, bk, bv, bo, posb, wbf, (float*)d_out);
}